// Round 5
// baseline (553.246 us; speedup 1.0000x reference)
//
#include <hip/hip_runtime.h>
#include <cstdint>
#include <cstddef>

#define S_LEN 2048
#define BATCH 2
#define HIDN  2048
#define NHEAD 16
#define DHEAD 128
#define NQKV  6144   // 3*NHEAD*DHEAD
#define MROWS 4096   // S_LEN*BATCH

typedef unsigned short u16;
typedef __attribute__((ext_vector_type(8))) __bf16 bf16x8;
typedef __attribute__((ext_vector_type(4))) float f32x4;

__device__ __forceinline__ float bf2f(u16 u) {
  union { uint32_t i; float f; } v; v.i = ((uint32_t)u) << 16; return v.f;
}
__device__ __forceinline__ u16 f2bf(float f) {
  union { float f; uint32_t i; } v; v.f = f;
  uint32_t r = v.i + 0x7fffu + ((v.i >> 16) & 1u);
  return (u16)(r >> 16);
}

__device__ __forceinline__ void async_cp16(const u16* g, u16* l) {
  __builtin_amdgcn_global_load_lds(
      (const __attribute__((address_space(1))) void*)g,
      (__attribute__((address_space(3))) void*)l, 16, 0, 0);
}

// ---------------- hidden canonicalize: fp32[N] -> bf16[N] --------------------
__global__ __launch_bounds__(256) void convert_hidden_kernel(
    const float* __restrict__ src, u16* __restrict__ out) {
  size_t c = (size_t)blockIdx.x * 256 + threadIdx.x;  // chunk of 8 elements
  const float4* in = (const float4*)(src + c * 8);
  float4 v0 = in[0], v1 = in[1];
  u16 t[8] = {f2bf(v0.x), f2bf(v0.y), f2bf(v0.z), f2bf(v0.w),
              f2bf(v1.x), f2bf(v1.y), f2bf(v1.z), f2bf(v1.w)};
  *(uint4*)&out[c * 8] = *(const uint4*)t;
}

// ---------------- transpose+cast: fp32 in[R][C] -> bf16 out[C][R] ------------
__global__ __launch_bounds__(256) void transpose_kernel(
    const float* __restrict__ in, u16* __restrict__ out, int R, int C) {
  __shared__ u16 tile[64][72];
  const int bx = blockIdx.x * 64;  // col base in `in`
  const int by = blockIdx.y * 64;  // row base in `in`
  const int lx = threadIdx.x & 15, ly = threadIdx.x >> 4;
#pragma unroll
  for (int i = 0; i < 4; i++) {
    int r = ly * 4 + i;
    float4 v = *(const float4*)&in[(size_t)(by + r) * C + bx + lx * 4];
    tile[r][lx * 4 + 0] = f2bf(v.x); tile[r][lx * 4 + 1] = f2bf(v.y);
    tile[r][lx * 4 + 2] = f2bf(v.z); tile[r][lx * 4 + 3] = f2bf(v.w);
  }
  __syncthreads();
#pragma unroll
  for (int i = 0; i < 4; i++) {
    int oc = ly * 4 + i;  // out row = bx + oc
    ushort4 o;
    o.x = tile[lx * 4 + 0][oc]; o.y = tile[lx * 4 + 1][oc];
    o.z = tile[lx * 4 + 2][oc]; o.w = tile[lx * 4 + 3][oc];
    *(ushort4*)&out[(size_t)(bx + oc) * R + by + lx * 4] = o;
  }
}

// =============================================================================
// 8-phase 128x256 GEMM core (T2 swizzle + T3/T4 counted vmcnt + T5 setprio)
// (unchanged from round 2 -- passed, qkv dropped out of top-5)
// =============================================================================

__device__ __forceinline__ int swz(int o) {
  return o ^ ((o >> 3) & 16) ^ ((o >> 4) & 0x60);
}

__device__ __forceinline__ bf16x8 rdfrag(const u16* ldsT, int row, int lhi16, int kk) {
  int off = row * 128 + kk * 64 + lhi16;
  off ^= ((off >> 3) & 16) ^ ((off >> 4) & 0x60);
  return *(const bf16x8*)((const char*)ldsT + off);
}

#define MFMA16(a, b, c) __builtin_amdgcn_mfma_f32_16x16x32_bf16(a, b, c, 0, 0, 0)

#define STAGE6(d, koff) do {                                  \
    async_cp16(gA[0] + (koff), lA[d] + wq);                   \
    async_cp16(gA[1] + (koff), lA[d] + 4096 + wq);            \
    async_cp16(gB[0] + (koff), lB[d] + wq);                   \
    async_cp16(gB[1] + (koff), lB[d] + 4096 + wq);            \
    async_cp16(gB[2] + (koff), lB[d] + 8192 + wq);            \
    async_cp16(gB[3] + (koff), lB[d] + 12288 + wq);           \
  } while (0)

#define KTILE(d, pre_koff) do {                                                 \
    bf16x8 a00, a01, a10, a11, b00, b01, b10, b11, b20, b21, b30, b31;          \
    a00 = rdfrag(lA[d], wm + llo,      lhi16, 0);                               \
    a01 = rdfrag(lA[d], wm + llo,      lhi16, 1);                               \
    a10 = rdfrag(lA[d], wm + 16 + llo, lhi16, 0);                               \
    a11 = rdfrag(lA[d], wm + 16 + llo, lhi16, 1);                               \
    b00 = rdfrag(lB[d], wn + llo,      lhi16, 0);                               \
    b01 = rdfrag(lB[d], wn + llo,      lhi16, 1);                               \
    b10 = rdfrag(lB[d], wn + 16 + llo, lhi16, 0);                               \
    b11 = rdfrag(lB[d], wn + 16 + llo, lhi16, 1);                               \
    __builtin_amdgcn_s_barrier();                                               \
    asm volatile("s_waitcnt lgkmcnt(0)" ::: "memory");                          \
    __builtin_amdgcn_sched_barrier(0);                                          \
    __builtin_amdgcn_s_setprio(1);                                              \
    acc[0][0] = MFMA16(a00, b00, acc[0][0]); acc[0][0] = MFMA16(a01, b01, acc[0][0]); \
    acc[0][1] = MFMA16(a00, b10, acc[0][1]); acc[0][1] = MFMA16(a01, b11, acc[0][1]); \
    acc[1][0] = MFMA16(a10, b00, acc[1][0]); acc[1][0] = MFMA16(a11, b01, acc[1][0]); \
    acc[1][1] = MFMA16(a10, b10, acc[1][1]); acc[1][1] = MFMA16(a11, b11, acc[1][1]); \
    __builtin_amdgcn_s_setprio(0);                                              \
    __builtin_amdgcn_s_barrier();                                               \
    b20 = rdfrag(lB[d], wn + 32 + llo, lhi16, 0);                               \
    b21 = rdfrag(lB[d], wn + 32 + llo, lhi16, 1);                               \
    b30 = rdfrag(lB[d], wn + 48 + llo, lhi16, 0);                               \
    b31 = rdfrag(lB[d], wn + 48 + llo, lhi16, 1);                               \
    __builtin_amdgcn_s_barrier();                                               \
    asm volatile("s_waitcnt lgkmcnt(0)" ::: "memory");                          \
    __builtin_amdgcn_sched_barrier(0);                                          \
    __builtin_amdgcn_s_setprio(1);                                              \
    acc[0][2] = MFMA16(a00, b20, acc[0][2]); acc[0][2] = MFMA16(a01, b21, acc[0][2]); \
    acc[0][3] = MFMA16(a00, b30, acc[0][3]); acc[0][3] = MFMA16(a01, b31, acc[0][3]); \
    acc[1][2] = MFMA16(a10, b20, acc[1][2]); acc[1][2] = MFMA16(a11, b21, acc[1][2]); \
    acc[1][3] = MFMA16(a10, b30, acc[1][3]); acc[1][3] = MFMA16(a11, b31, acc[1][3]); \
    __builtin_amdgcn_s_setprio(0);                                              \
    __builtin_amdgcn_s_barrier();                                               \
    a00 = rdfrag(lA[d], wm + 32 + llo, lhi16, 0);                               \
    a01 = rdfrag(lA[d], wm + 32 + llo, lhi16, 1);                               \
    a10 = rdfrag(lA[d], wm + 48 + llo, lhi16, 0);                               \
    a11 = rdfrag(lA[d], wm + 48 + llo, lhi16, 1);                               \
    __builtin_amdgcn_s_barrier();                                               \
    asm volatile("s_waitcnt lgkmcnt(0)" ::: "memory");                          \
    __builtin_amdgcn_sched_barrier(0);                                          \
    __builtin_amdgcn_s_setprio(1);                                              \
    acc[2][2] = MFMA16(a00, b20, acc[2][2]); acc[2][2] = MFMA16(a01, b21, acc[2][2]); \
    acc[2][3] = MFMA16(a00, b30, acc[2][3]); acc[2][3] = MFMA16(a01, b31, acc[2][3]); \
    acc[3][2] = MFMA16(a10, b20, acc[3][2]); acc[3][2] = MFMA16(a11, b21, acc[3][2]); \
    acc[3][3] = MFMA16(a10, b30, acc[3][3]); acc[3][3] = MFMA16(a11, b31, acc[3][3]); \
    __builtin_amdgcn_s_setprio(0);                                              \
    __builtin_amdgcn_s_barrier();                                               \
    STAGE6(d, pre_koff);                                                        \
    __builtin_amdgcn_s_barrier();                                               \
    __builtin_amdgcn_s_setprio(1);                                              \
    acc[2][0] = MFMA16(a00, b00, acc[2][0]); acc[2][0] = MFMA16(a01, b01, acc[2][0]); \
    acc[2][1] = MFMA16(a00, b10, acc[2][1]); acc[2][1] = MFMA16(a01, b11, acc[2][1]); \
    acc[3][0] = MFMA16(a10, b00, acc[3][0]); acc[3][0] = MFMA16(a11, b01, acc[3][0]); \
    acc[3][1] = MFMA16(a10, b10, acc[3][1]); acc[3][1] = MFMA16(a11, b11, acc[3][1]); \
    __builtin_amdgcn_s_setprio(0);                                              \
    asm volatile("s_waitcnt vmcnt(6)" ::: "memory");                            \
    __builtin_amdgcn_s_barrier();                                               \
  } while (0)

__device__ __forceinline__ void gemm_core_128x256(
    const u16* __restrict__ A, const u16* __restrict__ Bt,
    int m0, int n0, u16* lds, f32x4 (&acc)[4][4]) {
  const int tid = threadIdx.x;
  const int wid = tid >> 6, lane = tid & 63;
  const int llo = lane & 15, lhi16 = (lane >> 4) * 16;
  const int wm = (wid >> 2) * 64;
  const int wn = (wid & 3) * 64;
  const int K = HIDN;

  const u16* gA[2];
  const u16* gB[4];
#pragma unroll
  for (int q = 0; q < 2; ++q) {
    int off = q * 8192 + tid * 16;
    int s = swz(off);
    gA[q] = A + (size_t)(m0 + (s >> 7)) * K + ((s & 127) >> 1);
  }
#pragma unroll
  for (int q = 0; q < 4; ++q) {
    int off = q * 8192 + tid * 16;
    int s = swz(off);
    gB[q] = Bt + (size_t)(n0 + (s >> 7)) * K + ((s & 127) >> 1);
  }
  u16* lA[2] = { lds, lds + 24576 };
  u16* lB[2] = { lds + 8192, lds + 24576 + 8192 };
  const int wq = wid * 512;

#pragma unroll
  for (int i = 0; i < 4; ++i)
#pragma unroll
    for (int j = 0; j < 4; ++j) acc[i][j] = (f32x4){0.f, 0.f, 0.f, 0.f};

  STAGE6(0, 0);
  STAGE6(1, 64);
  asm volatile("s_waitcnt vmcnt(6)" ::: "memory");
  __builtin_amdgcn_s_barrier();

#pragma unroll 1
  for (int kt = 0; kt < 32; kt += 2) {
    int p0 = (kt + 2 < 32) ? (kt + 2) * 64 : 0;
    int p1 = (kt + 3 < 32) ? (kt + 3) * 64 : 0;
    KTILE(0, p0);
    KTILE(1, p1);
  }
}

// ---------------- QKV GEMM: [4096,2048] x Wt[6144,2048] + bias ---------------
__global__ __launch_bounds__(512, 2) void gemm_qkv8_kernel(
    const u16* __restrict__ A, const u16* __restrict__ Bt,
    const float* __restrict__ bias,
    u16* __restrict__ Qb, u16* __restrict__ Kb, u16* __restrict__ Vt) {
  __shared__ __align__(16) u16 lds[49152];  // 96KB
  int bid = blockIdx.x;
  int sb = (bid & 7) * 96 + (bid >> 3);
  int bx = sb >> 5, by = sb & 31;
  int m0 = by * 128, n0 = bx * 256;

  f32x4 acc[4][4];
  gemm_core_128x256(A, Bt, m0, n0, lds, acc);

  const int tid = threadIdx.x;
  const int wid = tid >> 6, lane = tid & 63;
  const int llo = lane & 15, lhi = lane >> 4;
  const int wm = (wid >> 2) * 64, wn = (wid & 3) * 64;

#pragma unroll
  for (int j = 0; j < 4; ++j) {
    int col = n0 + wn + j * 16 + llo;       // 0..6143
    int h = col / 384;
    int rr = col - h * 384;
    int part = rr >> 7;                     // 0=q 1=k 2=v
    int d = rr & 127;
    float bv = bias[col];
#pragma unroll
    for (int i = 0; i < 4; ++i) {
#pragma unroll
      for (int r = 0; r < 4; ++r) {
        int row = m0 + wm + i * 16 + lhi * 4 + r;  // 0..4095
        int s = row >> 1, b = row & 1;
        int bh = b * NHEAD + h;
        u16 o = f2bf(acc[i][j][r] + bv);
        if (part == 0)      Qb[((size_t)bh * S_LEN + s) * DHEAD + d] = o;
        else if (part == 1) Kb[((size_t)bh * S_LEN + s) * DHEAD + d] = o;
        else                Vt[((size_t)bh * DHEAD + d) * S_LEN + s] = o;
      }
    }
  }
}

// ------------- dense GEMM: ctx[4096,2048] x Wt[2048,2048] -> fp32 out --------
__global__ __launch_bounds__(512, 2) void gemm_dense8_kernel(
    const u16* __restrict__ A, const u16* __restrict__ Bt,
    float* __restrict__ out) {
  __shared__ __align__(16) u16 lds[49152];  // 96KB
  int bid = blockIdx.x;                      // 256 blocks = 32/XCD
  int sb = (bid & 7) * 32 + (bid >> 3);
  int bx = sb >> 5, by = sb & 31;
  int m0 = by * 128, n0 = bx * 256;

  f32x4 acc[4][4];
  gemm_core_128x256(A, Bt, m0, n0, lds, acc);

  const int tid = threadIdx.x;
  const int wid = tid >> 6, lane = tid & 63;
  const int llo = lane & 15, lhi = lane >> 4;
  const int wm = (wid >> 2) * 64, wn = (wid & 3) * 64;

#pragma unroll
  for (int i = 0; i < 4; ++i)
#pragma unroll
    for (int j = 0; j < 4; ++j) {
      int col = n0 + wn + j * 16 + llo;
#pragma unroll
      for (int r = 0; r < 4; ++r) {
        int row = m0 + wm + i * 16 + lhi * 4 + r;
        out[(size_t)row * HIDN + col] = acc[i][j][r];
      }
    }
}

// ---------------- flash attention (causal), one block per (q-tile, bh) -------
// 512 threads = 8 waves x 16 q-rows. Reg-prefetch K/V double-buffer (T14):
// next tile's global loads issued at step start into VGPRs, LDS write after
// the V-read barrier. Raw s_barrier (NO vmcnt drain) keeps prefetch in
// flight across barriers; lgkmcnt(0) asm guards ds_write->barrier->ds_read.
// Scale 1/sqrt(D) folded into exp args. setprio around MFMA clusters (T5).
__global__ __launch_bounds__(512, 4) void attn_kernel(
    const u16* __restrict__ Qb, const u16* __restrict__ Kb,
    const u16* __restrict__ Vt, u16* __restrict__ ctx) {
  const int bh = blockIdx.y;   // 0..31
  const int b = bh >> 4, h = bh & 15;
  // balance swizzle: co-resident pairs get qi and 15-qi -> ~17 steps per CU.
  const int qi = (b == 0) ? blockIdx.x : (15 - blockIdx.x);
  const int tid = threadIdx.x;
  const int wave = tid >> 6, lane = tid & 63;
  const int lhi = lane >> 4, llo = lane & 15;
  const int LP = 132;
  __shared__ __align__(16) u16 lds_kp[128 * 132];  // K tile, then P (aliased)
  __shared__ __align__(16) u16 lds_v[128 * 132];   // V^T tile [d][t]

  // ---- Q A-fragments in registers (once per block; wave owns 16 q-rows) ----
  bf16x8 aq[4];
  {
    const u16* qsrc = Qb + ((size_t)bh * S_LEN + qi * 128) * DHEAD;
#pragma unroll
    for (int kk = 0; kk < 4; kk++)
      aq[kk] = *(const bf16x8*)&qsrc[(size_t)(wave * 16 + llo) * DHEAD + kk * 32 + lhi * 8];
  }

  f32x4 oacc[8] = {};
  float mrow[4], lrow[4];
#pragma unroll
  for (int r = 0; r < 4; r++) { mrow[r] = -1e30f; lrow[r] = 0.f; }

  const float sc = 0.08838834764831845f;  // 1/sqrt(128)
  const u16* kbase = Kb + (size_t)bh * S_LEN * DHEAD;
  const u16* vbase = Vt + (size_t)bh * DHEAD * S_LEN;

  uint4 pk[4], pv[4];  // prefetch regs: 32KB K + 32KB V across 512 threads

  // prologue: tile 0 -> regs -> LDS
#pragma unroll
  for (int p = 0; p < 4; p++) {
    int idx = p * 512 + tid, r = idx >> 4, sg = (idx & 15) * 8;
    pk[p] = *(const uint4*)&kbase[(size_t)r * DHEAD + sg];
    pv[p] = *(const uint4*)&vbase[(size_t)r * S_LEN + sg];
  }
#pragma unroll
  for (int p = 0; p < 4; p++) {
    int idx = p * 512 + tid, r = idx >> 4, sg = (idx & 15) * 8;
    *(uint4*)&lds_kp[r * LP + sg] = pk[p];
    *(uint4*)&lds_v[r * LP + sg] = pv[p];
  }
  asm volatile("s_waitcnt lgkmcnt(0)" ::: "memory");
  __builtin_amdgcn_s_barrier();
  asm volatile("" ::: "memory");

  for (int kt = 0; kt <= qi; kt++) {
    const bool pf = (kt < qi);  // wave-uniform
    if (pf) {  // issue next tile's loads now; consumed only at tile end
      const u16* ksrc = kbase + (size_t)(kt + 1) * 128 * DHEAD;
      const u16* vsrc = vbase + (kt + 1) * 128;
#pragma unroll
      for (int p = 0; p < 4; p++) {
        int idx = p * 512 + tid, r = idx >> 4, sg = (idx & 15) * 8;
        pk[p] = *(const uint4*)&ksrc[(size_t)r * DHEAD + sg];
        pv[p] = *(const uint4*)&vsrc[(size_t)r * S_LEN + sg];
      }
    }

    // S = Q K^T  (wave owns 16 q-rows x 128 t-cols)
    f32x4 sacc[8] = {};
    __builtin_amdgcn_s_setprio(1);
#pragma unroll
    for (int kk = 0; kk < 4; kk++) {
#pragma unroll
      for (int j = 0; j < 8; j++) {
        bf16x8 bk = *(const bf16x8*)&lds_kp[(j * 16 + llo) * LP + kk * 32 + lhi * 8];
        sacc[j] = MFMA16(aq[kk], bk, sacc[j]);
      }
    }
    __builtin_amdgcn_s_setprio(0);
    asm volatile("" ::: "memory");
    __builtin_amdgcn_s_barrier();   // all waves done reading K (P will alias)
    asm volatile("" ::: "memory");

    if (kt == qi) {  // causal mask on diagonal tile (raw scores)
#pragma unroll
      for (int j = 0; j < 8; j++) {
        int coll = j * 16 + llo;
#pragma unroll
        for (int r = 0; r < 4; r++) {
          int rowl = wave * 16 + lhi * 4 + r;
          if (coll > rowl) sacc[j][r] = -1e30f;
        }
      }
    }

    // online softmax (scale folded into exp); oacc rescale fused in
#pragma unroll
    for (int r = 0; r < 4; r++) {
      float mx = sacc[0][r];
#pragma unroll
      for (int j = 1; j < 8; j++) mx = fmaxf(mx, sacc[j][r]);
#pragma unroll
      for (int off = 1; off < 16; off <<= 1)
        mx = fmaxf(mx, __shfl_xor(mx, off, 64));
      float mnew = fmaxf(mrow[r], mx);
      float al = __expf((mrow[r] - mnew) * sc);
      mrow[r] = mnew;
      float rs = 0.f;
#pragma unroll
      for (int j = 0; j < 8; j++) {
        float e = __expf((sacc[j][r] - mnew) * sc);
        sacc[j][r] = e;
        rs += e;
        oacc[j][r] *= al;
      }
#pragma unroll
      for (int off = 1; off < 16; off <<= 1)
        rs += __shfl_xor(rs, off, 64);
      lrow[r] = lrow[r] * al + rs;
    }

    // P -> LDS (wave-private rows; same-wave in-order LDS, no barrier needed)
#pragma unroll
    for (int j = 0; j < 8; j++)
#pragma unroll
      for (int r = 0; r < 4; r++)
        lds_kp[(wave * 16 + lhi * 4 + r) * LP + j * 16 + llo] = f2bf(sacc[j][r]);

    // O += P V
    __builtin_amdgcn_s_setprio(1);
#pragma unroll
    for (int kk = 0; kk < 4; kk++) {
      bf16x8 ap = *(const bf16x8*)&lds_kp[(wave * 16 + llo) * LP + kk * 32 + lhi * 8];
#pragma unroll
      for (int j = 0; j < 8; j++) {
        bf16x8 bv = *(const bf16x8*)&lds_v[(j * 16 + llo) * LP + kk * 32 + lhi * 8];
        oacc[j] = MFMA16(ap, bv, oacc[j]);
      }
    }
    __builtin_amdgcn_s_setprio(0);

    if (pf) {
      asm volatile("" ::: "memory");
      __builtin_amdgcn_s_barrier();   // all waves done reading V/P
      asm volatile("" ::: "memory");
#pragma unroll
      for (int p = 0; p < 4; p++) {   // prefetch regs -> LDS (vmcnt by dep)
        int idx = p * 512 + tid, r = idx >> 4, sg = (idx & 15) * 8;
        *(uint4*)&lds_kp[r * LP + sg] = pk[p];
        *(uint4*)&lds_v[r * LP + sg] = pv[p];
      }
      asm volatile("s_waitcnt lgkmcnt(0)" ::: "memory");
      __builtin_amdgcn_s_barrier();   // next tile visible
      asm volatile("" ::: "memory");
    }
  }

  // epilogue: O /= l, write ctx[s,b,h*128+d]
  float inv[4];
#pragma unroll
  for (int r = 0; r < 4; r++) inv[r] = 1.f / lrow[r];
#pragma unroll
  for (int j = 0; j < 8; j++) {
    int d = j * 16 + llo;
#pragma unroll
    for (int r = 0; r < 4; r++) {
      int s = qi * 128 + wave * 16 + lhi * 4 + r;
      ctx[((size_t)(s * BATCH + b)) * HIDN + h * DHEAD + d] = f2bf(oacc[j][r] * inv[r]);
    }
  }
}

// ---------------- bias tail: fp32 copy into output slot 1 --------------------
__global__ __launch_bounds__(256) void bias_copy_kernel(
    const float* __restrict__ bsrc, float* __restrict__ dst) {
  int i = blockIdx.x * 256 + threadIdx.x;
  if (i < HIDN) dst[i] = bsrc[i];
}

extern "C" void kernel_launch(void* const* d_in, const int* in_sizes, int n_in,
                              void* d_out, int out_size, void* d_ws, size_t ws_size,
                              hipStream_t stream) {
  int i_hid = 0, i_w1 = 2, i_b1 = 3, i_w2 = 4, i_b2 = 5;
  for (int i = 0; i < n_in; i++) {
    int s = in_sizes[i];
    if (s == MROWS * HIDN)      i_hid = i;
    else if (s == HIDN * NQKV)  i_w1 = i;
    else if (s == NQKV)         i_b1 = i;
    else if (s == HIDN)         i_b2 = i;
  }
  for (int i = n_in - 1; i >= 0; i--)
    if (in_sizes[i] == HIDN * HIDN) { i_w2 = i; break; }

  const float* hidden  = (const float*)d_in[i_hid];
  const float* W_qkv   = (const float*)d_in[i_w1];
  const float* b_qkv   = (const float*)d_in[i_b1];
  const float* W_dense = (const float*)d_in[i_w2];
  const float* b_dense = (const float*)d_in[i_b2];
  float* out = (float*)d_out;

  char* ws = (char*)d_ws;
  u16* Wq_t = (u16*)(ws);
  u16* ctx  = (u16*)(ws);
  u16* Wd_t = (u16*)(ws + 16777216);
  u16* Qb   = (u16*)(ws + 25165824);
  u16* Kb   = (u16*)(ws + 41943040);
  u16* Vt   = (u16*)(ws + 58720256);
  u16* hidden_c = (u16*)d_out;

  convert_hidden_kernel<<<dim3(MROWS * HIDN / 8 / 256), 256, 0, stream>>>(hidden, hidden_c);
  transpose_kernel<<<dim3(NQKV / 64, HIDN / 64), 256, 0, stream>>>(W_qkv, Wq_t, HIDN, NQKV);
  gemm_qkv8_kernel<<<dim3(768), dim3(512), 0, stream>>>(hidden_c, Wq_t, b_qkv, Qb, Kb, Vt);
  attn_kernel<<<dim3(S_LEN / 128, BATCH * NHEAD), dim3(512), 0, stream>>>(Qb, Kb, Vt, ctx);
  transpose_kernel<<<dim3(HIDN / 64, HIDN / 64), 256, 0, stream>>>(W_dense, Wd_t, HIDN, HIDN);
  gemm_dense8_kernel<<<dim3(256), dim3(512), 0, stream>>>(ctx, Wd_t, out);
  bias_copy_kernel<<<dim3(8), 256, 0, stream>>>(b_dense, out + (size_t)MROWS * HIDN);
}

// Round 6
// 534.142 us; speedup vs baseline: 1.0358x; 1.0358x over previous
//
#include <hip/hip_runtime.h>
#include <cstdint>
#include <cstddef>

#define S_LEN 2048
#define BATCH 2
#define HIDN  2048
#define NHEAD 16
#define DHEAD 128
#define NQKV  6144   // 3*NHEAD*DHEAD
#define MROWS 4096   // S_LEN*BATCH

typedef unsigned short u16;
typedef __attribute__((ext_vector_type(8))) __bf16 bf16x8;
typedef __attribute__((ext_vector_type(4))) float f32x4;

__device__ __forceinline__ float bf2f(u16 u) {
  union { uint32_t i; float f; } v; v.i = ((uint32_t)u) << 16; return v.f;
}
__device__ __forceinline__ u16 f2bf(float f) {
  union { float f; uint32_t i; } v; v.f = f;
  uint32_t r = v.i + 0x7fffu + ((v.i >> 16) & 1u);
  return (u16)(r >> 16);
}

__device__ __forceinline__ void async_cp16(const u16* g, u16* l) {
  __builtin_amdgcn_global_load_lds(
      (const __attribute__((address_space(1))) void*)g,
      (__attribute__((address_space(3))) void*)l, 16, 0, 0);
}

// ---------------- hidden canonicalize: fp32[N] -> bf16[N] --------------------
__global__ __launch_bounds__(256) void convert_hidden_kernel(
    const float* __restrict__ src, u16* __restrict__ out) {
  size_t c = (size_t)blockIdx.x * 256 + threadIdx.x;  // chunk of 8 elements
  const float4* in = (const float4*)(src + c * 8);
  float4 v0 = in[0], v1 = in[1];
  u16 t[8] = {f2bf(v0.x), f2bf(v0.y), f2bf(v0.z), f2bf(v0.w),
              f2bf(v1.x), f2bf(v1.y), f2bf(v1.z), f2bf(v1.w)};
  *(uint4*)&out[c * 8] = *(const uint4*)t;
}

// ---------------- transpose+cast: fp32 in[R][C] -> bf16 out[C][R] ------------
__global__ __launch_bounds__(256) void transpose_kernel(
    const float* __restrict__ in, u16* __restrict__ out, int R, int C) {
  __shared__ u16 tile[64][72];
  const int bx = blockIdx.x * 64;  // col base in `in`
  const int by = blockIdx.y * 64;  // row base in `in`
  const int lx = threadIdx.x & 15, ly = threadIdx.x >> 4;
#pragma unroll
  for (int i = 0; i < 4; i++) {
    int r = ly * 4 + i;
    float4 v = *(const float4*)&in[(size_t)(by + r) * C + bx + lx * 4];
    tile[r][lx * 4 + 0] = f2bf(v.x); tile[r][lx * 4 + 1] = f2bf(v.y);
    tile[r][lx * 4 + 2] = f2bf(v.z); tile[r][lx * 4 + 3] = f2bf(v.w);
  }
  __syncthreads();
#pragma unroll
  for (int i = 0; i < 4; i++) {
    int oc = ly * 4 + i;  // out row = bx + oc
    ushort4 o;
    o.x = tile[lx * 4 + 0][oc]; o.y = tile[lx * 4 + 1][oc];
    o.z = tile[lx * 4 + 2][oc]; o.w = tile[lx * 4 + 3][oc];
    *(ushort4*)&out[(size_t)(bx + oc) * R + by + lx * 4] = o;
  }
}

// =============================================================================
// 8-phase 128x256 GEMM core (T2 swizzle + T3/T4 counted vmcnt + T5 setprio)
// (unchanged from round 2 -- passed)
// =============================================================================

__device__ __forceinline__ int swz(int o) {
  return o ^ ((o >> 3) & 16) ^ ((o >> 4) & 0x60);
}

__device__ __forceinline__ bf16x8 rdfrag(const u16* ldsT, int row, int lhi16, int kk) {
  int off = row * 128 + kk * 64 + lhi16;
  off ^= ((off >> 3) & 16) ^ ((off >> 4) & 0x60);
  return *(const bf16x8*)((const char*)ldsT + off);
}

#define MFMA16(a, b, c) __builtin_amdgcn_mfma_f32_16x16x32_bf16(a, b, c, 0, 0, 0)

#define STAGE6(d, koff) do {                                  \
    async_cp16(gA[0] + (koff), lA[d] + wq);                   \
    async_cp16(gA[1] + (koff), lA[d] + 4096 + wq);            \
    async_cp16(gB[0] + (koff), lB[d] + wq);                   \
    async_cp16(gB[1] + (koff), lB[d] + 4096 + wq);            \
    async_cp16(gB[2] + (koff), lB[d] + 8192 + wq);            \
    async_cp16(gB[3] + (koff), lB[d] + 12288 + wq);           \
  } while (0)

#define KTILE(d, pre_koff) do {                                                 \
    bf16x8 a00, a01, a10, a11, b00, b01, b10, b11, b20, b21, b30, b31;          \
    a00 = rdfrag(lA[d], wm + llo,      lhi16, 0);                               \
    a01 = rdfrag(lA[d], wm + llo,      lhi16, 1);                               \
    a10 = rdfrag(lA[d], wm + 16 + llo, lhi16, 0);                               \
    a11 = rdfrag(lA[d], wm + 16 + llo, lhi16, 1);                               \
    b00 = rdfrag(lB[d], wn + llo,      lhi16, 0);                               \
    b01 = rdfrag(lB[d], wn + llo,      lhi16, 1);                               \
    b10 = rdfrag(lB[d], wn + 16 + llo, lhi16, 0);                               \
    b11 = rdfrag(lB[d], wn + 16 + llo, lhi16, 1);                               \
    __builtin_amdgcn_s_barrier();                                               \
    asm volatile("s_waitcnt lgkmcnt(0)" ::: "memory");                          \
    __builtin_amdgcn_sched_barrier(0);                                          \
    __builtin_amdgcn_s_setprio(1);                                              \
    acc[0][0] = MFMA16(a00, b00, acc[0][0]); acc[0][0] = MFMA16(a01, b01, acc[0][0]); \
    acc[0][1] = MFMA16(a00, b10, acc[0][1]); acc[0][1] = MFMA16(a01, b11, acc[0][1]); \
    acc[1][0] = MFMA16(a10, b00, acc[1][0]); acc[1][0] = MFMA16(a11, b01, acc[1][0]); \
    acc[1][1] = MFMA16(a10, b10, acc[1][1]); acc[1][1] = MFMA16(a11, b11, acc[1][1]); \
    __builtin_amdgcn_s_setprio(0);                                              \
    __builtin_amdgcn_s_barrier();                                               \
    b20 = rdfrag(lB[d], wn + 32 + llo, lhi16, 0);                               \
    b21 = rdfrag(lB[d], wn + 32 + llo, lhi16, 1);                               \
    b30 = rdfrag(lB[d], wn + 48 + llo, lhi16, 0);                               \
    b31 = rdfrag(lB[d], wn + 48 + llo, lhi16, 1);                               \
    __builtin_amdgcn_s_barrier();                                               \
    asm volatile("s_waitcnt lgkmcnt(0)" ::: "memory");                          \
    __builtin_amdgcn_sched_barrier(0);                                          \
    __builtin_amdgcn_s_setprio(1);                                              \
    acc[0][2] = MFMA16(a00, b20, acc[0][2]); acc[0][2] = MFMA16(a01, b21, acc[0][2]); \
    acc[0][3] = MFMA16(a00, b30, acc[0][3]); acc[0][3] = MFMA16(a01, b31, acc[0][3]); \
    acc[1][2] = MFMA16(a10, b20, acc[1][2]); acc[1][2] = MFMA16(a11, b21, acc[1][2]); \
    acc[1][3] = MFMA16(a10, b30, acc[1][3]); acc[1][3] = MFMA16(a11, b31, acc[1][3]); \
    __builtin_amdgcn_s_setprio(0);                                              \
    __builtin_amdgcn_s_barrier();                                               \
    a00 = rdfrag(lA[d], wm + 32 + llo, lhi16, 0);                               \
    a01 = rdfrag(lA[d], wm + 32 + llo, lhi16, 1);                               \
    a10 = rdfrag(lA[d], wm + 48 + llo, lhi16, 0);                               \
    a11 = rdfrag(lA[d], wm + 48 + llo, lhi16, 1);                               \
    __builtin_amdgcn_s_barrier();                                               \
    asm volatile("s_waitcnt lgkmcnt(0)" ::: "memory");                          \
    __builtin_amdgcn_sched_barrier(0);                                          \
    __builtin_amdgcn_s_setprio(1);                                              \
    acc[2][2] = MFMA16(a00, b20, acc[2][2]); acc[2][2] = MFMA16(a01, b21, acc[2][2]); \
    acc[2][3] = MFMA16(a00, b30, acc[2][3]); acc[2][3] = MFMA16(a01, b31, acc[2][3]); \
    acc[3][2] = MFMA16(a10, b20, acc[3][2]); acc[3][2] = MFMA16(a11, b21, acc[3][2]); \
    acc[3][3] = MFMA16(a10, b30, acc[3][3]); acc[3][3] = MFMA16(a11, b31, acc[3][3]); \
    __builtin_amdgcn_s_setprio(0);                                              \
    __builtin_amdgcn_s_barrier();                                               \
    STAGE6(d, pre_koff);                                                        \
    __builtin_amdgcn_s_barrier();                                               \
    __builtin_amdgcn_s_setprio(1);                                              \
    acc[2][0] = MFMA16(a00, b00, acc[2][0]); acc[2][0] = MFMA16(a01, b01, acc[2][0]); \
    acc[2][1] = MFMA16(a00, b10, acc[2][1]); acc[2][1] = MFMA16(a01, b11, acc[2][1]); \
    acc[3][0] = MFMA16(a10, b00, acc[3][0]); acc[3][0] = MFMA16(a11, b01, acc[3][0]); \
    acc[3][1] = MFMA16(a10, b10, acc[3][1]); acc[3][1] = MFMA16(a11, b11, acc[3][1]); \
    __builtin_amdgcn_s_setprio(0);                                              \
    asm volatile("s_waitcnt vmcnt(6)" ::: "memory");                            \
    __builtin_amdgcn_s_barrier();                                               \
  } while (0)

__device__ __forceinline__ void gemm_core_128x256(
    const u16* __restrict__ A, const u16* __restrict__ Bt,
    int m0, int n0, u16* lds, f32x4 (&acc)[4][4]) {
  const int tid = threadIdx.x;
  const int wid = tid >> 6, lane = tid & 63;
  const int llo = lane & 15, lhi16 = (lane >> 4) * 16;
  const int wm = (wid >> 2) * 64;
  const int wn = (wid & 3) * 64;
  const int K = HIDN;

  const u16* gA[2];
  const u16* gB[4];
#pragma unroll
  for (int q = 0; q < 2; ++q) {
    int off = q * 8192 + tid * 16;
    int s = swz(off);
    gA[q] = A + (size_t)(m0 + (s >> 7)) * K + ((s & 127) >> 1);
  }
#pragma unroll
  for (int q = 0; q < 4; ++q) {
    int off = q * 8192 + tid * 16;
    int s = swz(off);
    gB[q] = Bt + (size_t)(n0 + (s >> 7)) * K + ((s & 127) >> 1);
  }
  u16* lA[2] = { lds, lds + 24576 };
  u16* lB[2] = { lds + 8192, lds + 24576 + 8192 };
  const int wq = wid * 512;

#pragma unroll
  for (int i = 0; i < 4; ++i)
#pragma unroll
    for (int j = 0; j < 4; ++j) acc[i][j] = (f32x4){0.f, 0.f, 0.f, 0.f};

  STAGE6(0, 0);
  STAGE6(1, 64);
  asm volatile("s_waitcnt vmcnt(6)" ::: "memory");
  __builtin_amdgcn_s_barrier();

#pragma unroll 1
  for (int kt = 0; kt < 32; kt += 2) {
    int p0 = (kt + 2 < 32) ? (kt + 2) * 64 : 0;
    int p1 = (kt + 3 < 32) ? (kt + 3) * 64 : 0;
    KTILE(0, p0);
    KTILE(1, p1);
  }
}

// ---------------- QKV GEMM: [4096,2048] x Wt[6144,2048] + bias ---------------
__global__ __launch_bounds__(512, 2) void gemm_qkv8_kernel(
    const u16* __restrict__ A, const u16* __restrict__ Bt,
    const float* __restrict__ bias,
    u16* __restrict__ Qb, u16* __restrict__ Kb, u16* __restrict__ Vt) {
  __shared__ __align__(16) u16 lds[49152];  // 96KB
  int bid = blockIdx.x;
  int sb = (bid & 7) * 96 + (bid >> 3);
  int bx = sb >> 5, by = sb & 31;
  int m0 = by * 128, n0 = bx * 256;

  f32x4 acc[4][4];
  gemm_core_128x256(A, Bt, m0, n0, lds, acc);

  const int tid = threadIdx.x;
  const int wid = tid >> 6, lane = tid & 63;
  const int llo = lane & 15, lhi = lane >> 4;
  const int wm = (wid >> 2) * 64, wn = (wid & 3) * 64;

#pragma unroll
  for (int j = 0; j < 4; ++j) {
    int col = n0 + wn + j * 16 + llo;       // 0..6143
    int h = col / 384;
    int rr = col - h * 384;
    int part = rr >> 7;                     // 0=q 1=k 2=v
    int d = rr & 127;
    float bv = bias[col];
#pragma unroll
    for (int i = 0; i < 4; ++i) {
#pragma unroll
      for (int r = 0; r < 4; ++r) {
        int row = m0 + wm + i * 16 + lhi * 4 + r;  // 0..4095
        int s = row >> 1, b = row & 1;
        int bh = b * NHEAD + h;
        u16 o = f2bf(acc[i][j][r] + bv);
        if (part == 0)      Qb[((size_t)bh * S_LEN + s) * DHEAD + d] = o;
        else if (part == 1) Kb[((size_t)bh * S_LEN + s) * DHEAD + d] = o;
        else                Vt[((size_t)bh * DHEAD + d) * S_LEN + s] = o;
      }
    }
  }
}

// ------------- dense GEMM: ctx[4096,2048] x Wt[2048,2048] -> fp32 out --------
__global__ __launch_bounds__(512, 2) void gemm_dense8_kernel(
    const u16* __restrict__ A, const u16* __restrict__ Bt,
    float* __restrict__ out) {
  __shared__ __align__(16) u16 lds[49152];  // 96KB
  int bid = blockIdx.x;                      // 256 blocks = 32/XCD
  int sb = (bid & 7) * 32 + (bid >> 3);
  int bx = sb >> 5, by = sb & 31;
  int m0 = by * 128, n0 = bx * 256;

  f32x4 acc[4][4];
  gemm_core_128x256(A, Bt, m0, n0, lds, acc);

  const int tid = threadIdx.x;
  const int wid = tid >> 6, lane = tid & 63;
  const int llo = lane & 15, lhi = lane >> 4;
  const int wm = (wid >> 2) * 64, wn = (wid & 3) * 64;

#pragma unroll
  for (int i = 0; i < 4; ++i)
#pragma unroll
    for (int j = 0; j < 4; ++j) {
      int col = n0 + wn + j * 16 + llo;
#pragma unroll
      for (int r = 0; r < 4; ++r) {
        int row = m0 + wm + i * 16 + lhi * 4 + r;
        out[(size_t)row * HIDN + col] = acc[i][j][r];
      }
    }
}

// ---------------- flash attention (causal), one block per (q-tile, bh) -------
// 512 threads = 8 waves x 16 q-rows. Reg-prefetch K/V double-buffer (T14).
// __launch_bounds__(512, 2): 256-VGPR budget. Round-5's (512,4) forced a
// 64-VGPR budget -> full scratch spill (WRITE_SIZE 27->379MB, 228us). The
// prefetch design needs ~150-200 VGPRs; occupancy 8 waves/CU (2/EU).
__global__ __launch_bounds__(512, 2) void attn_kernel(
    const u16* __restrict__ Qb, const u16* __restrict__ Kb,
    const u16* __restrict__ Vt, u16* __restrict__ ctx) {
  const int bh = blockIdx.y;   // 0..31
  const int b = bh >> 4, h = bh & 15;
  // balance swizzle: co-resident pairs get qi and 15-qi -> ~17 steps per CU.
  const int qi = (b == 0) ? blockIdx.x : (15 - blockIdx.x);
  const int tid = threadIdx.x;
  const int wave = tid >> 6, lane = tid & 63;
  const int lhi = lane >> 4, llo = lane & 15;
  const int LP = 132;
  __shared__ __align__(16) u16 lds_kp[128 * 132];  // K tile, then P (aliased)
  __shared__ __align__(16) u16 lds_v[128 * 132];   // V^T tile [d][t]

  // ---- Q A-fragments in registers (once per block; wave owns 16 q-rows) ----
  bf16x8 aq[4];
  {
    const u16* qsrc = Qb + ((size_t)bh * S_LEN + qi * 128) * DHEAD;
#pragma unroll
    for (int kk = 0; kk < 4; kk++)
      aq[kk] = *(const bf16x8*)&qsrc[(size_t)(wave * 16 + llo) * DHEAD + kk * 32 + lhi * 8];
  }

  f32x4 oacc[8] = {};
  float mrow[4], lrow[4];
#pragma unroll
  for (int r = 0; r < 4; r++) { mrow[r] = -1e30f; lrow[r] = 0.f; }

  const float sc = 0.08838834764831845f;  // 1/sqrt(128)
  const u16* kbase = Kb + (size_t)bh * S_LEN * DHEAD;
  const u16* vbase = Vt + (size_t)bh * DHEAD * S_LEN;

  uint4 pk[4], pv[4];  // prefetch regs: 32KB K + 32KB V across 512 threads

  // prologue: tile 0 -> regs -> LDS
#pragma unroll
  for (int p = 0; p < 4; p++) {
    int idx = p * 512 + tid, r = idx >> 4, sg = (idx & 15) * 8;
    pk[p] = *(const uint4*)&kbase[(size_t)r * DHEAD + sg];
    pv[p] = *(const uint4*)&vbase[(size_t)r * S_LEN + sg];
  }
#pragma unroll
  for (int p = 0; p < 4; p++) {
    int idx = p * 512 + tid, r = idx >> 4, sg = (idx & 15) * 8;
    *(uint4*)&lds_kp[r * LP + sg] = pk[p];
    *(uint4*)&lds_v[r * LP + sg] = pv[p];
  }
  asm volatile("s_waitcnt lgkmcnt(0)" ::: "memory");
  __builtin_amdgcn_s_barrier();
  asm volatile("" ::: "memory");

  for (int kt = 0; kt <= qi; kt++) {
    const bool pf = (kt < qi);  // wave-uniform
    if (pf) {  // issue next tile's loads now; consumed only at tile end
      const u16* ksrc = kbase + (size_t)(kt + 1) * 128 * DHEAD;
      const u16* vsrc = vbase + (kt + 1) * 128;
#pragma unroll
      for (int p = 0; p < 4; p++) {
        int idx = p * 512 + tid, r = idx >> 4, sg = (idx & 15) * 8;
        pk[p] = *(const uint4*)&ksrc[(size_t)r * DHEAD + sg];
        pv[p] = *(const uint4*)&vsrc[(size_t)r * S_LEN + sg];
      }
    }

    // S = Q K^T  (wave owns 16 q-rows x 128 t-cols)
    f32x4 sacc[8] = {};
    __builtin_amdgcn_s_setprio(1);
#pragma unroll
    for (int kk = 0; kk < 4; kk++) {
#pragma unroll
      for (int j = 0; j < 8; j++) {
        bf16x8 bk = *(const bf16x8*)&lds_kp[(j * 16 + llo) * LP + kk * 32 + lhi * 8];
        sacc[j] = MFMA16(aq[kk], bk, sacc[j]);
      }
    }
    __builtin_amdgcn_s_setprio(0);
    asm volatile("" ::: "memory");
    __builtin_amdgcn_s_barrier();   // all waves done reading K (P will alias)
    asm volatile("" ::: "memory");

    if (kt == qi) {  // causal mask on diagonal tile (raw scores)
#pragma unroll
      for (int j = 0; j < 8; j++) {
        int coll = j * 16 + llo;
#pragma unroll
        for (int r = 0; r < 4; r++) {
          int rowl = wave * 16 + lhi * 4 + r;
          if (coll > rowl) sacc[j][r] = -1e30f;
        }
      }
    }

    // online softmax (scale folded into exp); oacc rescale fused in
#pragma unroll
    for (int r = 0; r < 4; r++) {
      float mx = sacc[0][r];
#pragma unroll
      for (int j = 1; j < 8; j++) mx = fmaxf(mx, sacc[j][r]);
#pragma unroll
      for (int off = 1; off < 16; off <<= 1)
        mx = fmaxf(mx, __shfl_xor(mx, off, 64));
      float mnew = fmaxf(mrow[r], mx);
      float al = __expf((mrow[r] - mnew) * sc);
      mrow[r] = mnew;
      float rs = 0.f;
#pragma unroll
      for (int j = 0; j < 8; j++) {
        float e = __expf((sacc[j][r] - mnew) * sc);
        sacc[j][r] = e;
        rs += e;
        oacc[j][r] *= al;
      }
#pragma unroll
      for (int off = 1; off < 16; off <<= 1)
        rs += __shfl_xor(rs, off, 64);
      lrow[r] = lrow[r] * al + rs;
    }

    // P -> LDS (wave-private rows; same-wave in-order LDS, no barrier needed)
#pragma unroll
    for (int j = 0; j < 8; j++)
#pragma unroll
      for (int r = 0; r < 4; r++)
        lds_kp[(wave * 16 + lhi * 4 + r) * LP + j * 16 + llo] = f2bf(sacc[j][r]);

    // O += P V
    __builtin_amdgcn_s_setprio(1);
#pragma unroll
    for (int kk = 0; kk < 4; kk++) {
      bf16x8 ap = *(const bf16x8*)&lds_kp[(wave * 16 + llo) * LP + kk * 32 + lhi * 8];
#pragma unroll
      for (int j = 0; j < 8; j++) {
        bf16x8 bv = *(const bf16x8*)&lds_v[(j * 16 + llo) * LP + kk * 32 + lhi * 8];
        oacc[j] = MFMA16(ap, bv, oacc[j]);
      }
    }
    __builtin_amdgcn_s_setprio(0);

    if (pf) {
      asm volatile("" ::: "memory");
      __builtin_amdgcn_s_barrier();   // all waves done reading V/P
      asm volatile("" ::: "memory");
#pragma unroll
      for (int p = 0; p < 4; p++) {   // prefetch regs -> LDS (vmcnt by dep)
        int idx = p * 512 + tid, r = idx >> 4, sg = (idx & 15) * 8;
        *(uint4*)&lds_kp[r * LP + sg] = pk[p];
        *(uint4*)&lds_v[r * LP + sg] = pv[p];
      }
      asm volatile("s_waitcnt lgkmcnt(0)" ::: "memory");
      __builtin_amdgcn_s_barrier();   // next tile visible
      asm volatile("" ::: "memory");
    }
  }

  // epilogue: O /= l, write ctx[s,b,h*128+d]
  float inv[4];
#pragma unroll
  for (int r = 0; r < 4; r++) inv[r] = 1.f / lrow[r];
#pragma unroll
  for (int j = 0; j < 8; j++) {
    int d = j * 16 + llo;
#pragma unroll
    for (int r = 0; r < 4; r++) {
      int s = qi * 128 + wave * 16 + lhi * 4 + r;
      ctx[((size_t)(s * BATCH + b)) * HIDN + h * DHEAD + d] = f2bf(oacc[j][r] * inv[r]);
    }
  }
}

// ---------------- bias tail: fp32 copy into output slot 1 --------------------
__global__ __launch_bounds__(256) void bias_copy_kernel(
    const float* __restrict__ bsrc, float* __restrict__ dst) {
  int i = blockIdx.x * 256 + threadIdx.x;
  if (i < HIDN) dst[i] = bsrc[i];
}

extern "C" void kernel_launch(void* const* d_in, const int* in_sizes, int n_in,
                              void* d_out, int out_size, void* d_ws, size_t ws_size,
                              hipStream_t stream) {
  int i_hid = 0, i_w1 = 2, i_b1 = 3, i_w2 = 4, i_b2 = 5;
  for (int i = 0; i < n_in; i++) {
    int s = in_sizes[i];
    if (s == MROWS * HIDN)      i_hid = i;
    else if (s == HIDN * NQKV)  i_w1 = i;
    else if (s == NQKV)         i_b1 = i;
    else if (s == HIDN)         i_b2 = i;
  }
  for (int i = n_in - 1; i >= 0; i--)
    if (in_sizes[i] == HIDN * HIDN) { i_w2 = i; break; }

  const float* hidden  = (const float*)d_in[i_hid];
  const float* W_qkv   = (const float*)d_in[i_w1];
  const float* b_qkv   = (const float*)d_in[i_b1];
  const float* W_dense = (const float*)d_in[i_w2];
  const float* b_dense = (const float*)d_in[i_b2];
  float* out = (float*)d_out;

  char* ws = (char*)d_ws;
  u16* Wq_t = (u16*)(ws);
  u16* ctx  = (u16*)(ws);
  u16* Wd_t = (u16*)(ws + 16777216);
  u16* Qb   = (u16*)(ws + 25165824);
  u16* Kb   = (u16*)(ws + 41943040);
  u16* Vt   = (u16*)(ws + 58720256);
  u16* hidden_c = (u16*)d_out;

  convert_hidden_kernel<<<dim3(MROWS * HIDN / 8 / 256), 256, 0, stream>>>(hidden, hidden_c);
  transpose_kernel<<<dim3(NQKV / 64, HIDN / 64), 256, 0, stream>>>(W_qkv, Wq_t, HIDN, NQKV);
  gemm_qkv8_kernel<<<dim3(768), dim3(512), 0, stream>>>(hidden_c, Wq_t, b_qkv, Qb, Kb, Vt);
  attn_kernel<<<dim3(S_LEN / 128, BATCH * NHEAD), dim3(512), 0, stream>>>(Qb, Kb, Vt, ctx);
  transpose_kernel<<<dim3(HIDN / 64, HIDN / 64), 256, 0, stream>>>(W_dense, Wd_t, HIDN, HIDN);
  gemm_dense8_kernel<<<dim3(256), dim3(512), 0, stream>>>(ctx, Wd_t, out);
  bias_copy_kernel<<<dim3(8), 256, 0, stream>>>(b_dense, out + (size_t)MROWS * HIDN);
}

// Round 8
// 456.793 us; speedup vs baseline: 1.2112x; 1.1693x over previous
//
#include <hip/hip_runtime.h>
#include <cstdint>
#include <cstddef>

#define S_LEN 2048
#define BATCH 2
#define HIDN  2048
#define NHEAD 16
#define DHEAD 128
#define NQKV  6144   // 3*NHEAD*DHEAD
#define MROWS 4096   // S_LEN*BATCH

typedef unsigned short u16;
typedef __attribute__((ext_vector_type(8))) __bf16 bf16x8;
typedef __attribute__((ext_vector_type(4))) float f32x4;

__device__ __forceinline__ float bf2f(u16 u) {
  union { uint32_t i; float f; } v; v.i = ((uint32_t)u) << 16; return v.f;
}
__device__ __forceinline__ u16 f2bf(float f) {
  union { float f; uint32_t i; } v; v.f = f;
  uint32_t r = v.i + 0x7fffu + ((v.i >> 16) & 1u);
  return (u16)(r >> 16);
}

__device__ __forceinline__ void async_cp16(const u16* g, u16* l) {
  __builtin_amdgcn_global_load_lds(
      (const __attribute__((address_space(1))) void*)g,
      (__attribute__((address_space(3))) void*)l, 16, 0, 0);
}

// ---------------- hidden canonicalize: fp32[N] -> bf16[N] --------------------
__global__ __launch_bounds__(256) void convert_hidden_kernel(
    const float* __restrict__ src, u16* __restrict__ out) {
  size_t c = (size_t)blockIdx.x * 256 + threadIdx.x;  // chunk of 8 elements
  const float4* in = (const float4*)(src + c * 8);
  float4 v0 = in[0], v1 = in[1];
  u16 t[8] = {f2bf(v0.x), f2bf(v0.y), f2bf(v0.z), f2bf(v0.w),
              f2bf(v1.x), f2bf(v1.y), f2bf(v1.z), f2bf(v1.w)};
  *(uint4*)&out[c * 8] = *(const uint4*)t;
}

// ---------------- transpose+cast: fp32 in[R][C] -> bf16 out[C][R] ------------
__global__ __launch_bounds__(256) void transpose_kernel(
    const float* __restrict__ in, u16* __restrict__ out, int R, int C) {
  __shared__ u16 tile[64][72];
  const int bx = blockIdx.x * 64;  // col base in `in`
  const int by = blockIdx.y * 64;  // row base in `in`
  const int lx = threadIdx.x & 15, ly = threadIdx.x >> 4;
#pragma unroll
  for (int i = 0; i < 4; i++) {
    int r = ly * 4 + i;
    float4 v = *(const float4*)&in[(size_t)(by + r) * C + bx + lx * 4];
    tile[r][lx * 4 + 0] = f2bf(v.x); tile[r][lx * 4 + 1] = f2bf(v.y);
    tile[r][lx * 4 + 2] = f2bf(v.z); tile[r][lx * 4 + 3] = f2bf(v.w);
  }
  __syncthreads();
#pragma unroll
  for (int i = 0; i < 4; i++) {
    int oc = ly * 4 + i;  // out row = bx + oc
    ushort4 o;
    o.x = tile[lx * 4 + 0][oc]; o.y = tile[lx * 4 + 1][oc];
    o.z = tile[lx * 4 + 2][oc]; o.w = tile[lx * 4 + 3][oc];
    *(ushort4*)&out[(size_t)(bx + oc) * R + by + lx * 4] = o;
  }
}

// =============================================================================
// 8-phase 128x256 GEMM core (T2 swizzle + T3/T4 counted vmcnt + T5 setprio)
// (unchanged -- passed on HW)
// =============================================================================

__device__ __forceinline__ int swz(int o) {
  return o ^ ((o >> 3) & 16) ^ ((o >> 4) & 0x60);
}

__device__ __forceinline__ bf16x8 rdfrag(const u16* ldsT, int row, int lhi16, int kk) {
  int off = row * 128 + kk * 64 + lhi16;
  off ^= ((off >> 3) & 16) ^ ((off >> 4) & 0x60);
  return *(const bf16x8*)((const char*)ldsT + off);
}

#define MFMA16(a, b, c) __builtin_amdgcn_mfma_f32_16x16x32_bf16(a, b, c, 0, 0, 0)

#define STAGE6(d, koff) do {                                  \
    async_cp16(gA[0] + (koff), lA[d] + wq);                   \
    async_cp16(gA[1] + (koff), lA[d] + 4096 + wq);            \
    async_cp16(gB[0] + (koff), lB[d] + wq);                   \
    async_cp16(gB[1] + (koff), lB[d] + 4096 + wq);            \
    async_cp16(gB[2] + (koff), lB[d] + 8192 + wq);            \
    async_cp16(gB[3] + (koff), lB[d] + 12288 + wq);           \
  } while (0)

#define KTILE(d, pre_koff) do {                                                 \
    bf16x8 a00, a01, a10, a11, b00, b01, b10, b11, b20, b21, b30, b31;          \
    a00 = rdfrag(lA[d], wm + llo,      lhi16, 0);                               \
    a01 = rdfrag(lA[d], wm + llo,      lhi16, 1);                               \
    a10 = rdfrag(lA[d], wm + 16 + llo, lhi16, 0);                               \
    a11 = rdfrag(lA[d], wm + 16 + llo, lhi16, 1);                               \
    b00 = rdfrag(lB[d], wn + llo,      lhi16, 0);                               \
    b01 = rdfrag(lB[d], wn + llo,      lhi16, 1);                               \
    b10 = rdfrag(lB[d], wn + 16 + llo, lhi16, 0);                               \
    b11 = rdfrag(lB[d], wn + 16 + llo, lhi16, 1);                               \
    __builtin_amdgcn_s_barrier();                                               \
    asm volatile("s_waitcnt lgkmcnt(0)" ::: "memory");                          \
    __builtin_amdgcn_sched_barrier(0);                                          \
    __builtin_amdgcn_s_setprio(1);                                              \
    acc[0][0] = MFMA16(a00, b00, acc[0][0]); acc[0][0] = MFMA16(a01, b01, acc[0][0]); \
    acc[0][1] = MFMA16(a00, b10, acc[0][1]); acc[0][1] = MFMA16(a01, b11, acc[0][1]); \
    acc[1][0] = MFMA16(a10, b00, acc[1][0]); acc[1][0] = MFMA16(a11, b01, acc[1][0]); \
    acc[1][1] = MFMA16(a10, b10, acc[1][1]); acc[1][1] = MFMA16(a11, b11, acc[1][1]); \
    __builtin_amdgcn_s_setprio(0);                                              \
    __builtin_amdgcn_s_barrier();                                               \
    b20 = rdfrag(lB[d], wn + 32 + llo, lhi16, 0);                               \
    b21 = rdfrag(lB[d], wn + 32 + llo, lhi16, 1);                               \
    b30 = rdfrag(lB[d], wn + 48 + llo, lhi16, 0);                               \
    b31 = rdfrag(lB[d], wn + 48 + llo, lhi16, 1);                               \
    __builtin_amdgcn_s_barrier();                                               \
    asm volatile("s_waitcnt lgkmcnt(0)" ::: "memory");                          \
    __builtin_amdgcn_sched_barrier(0);                                          \
    __builtin_amdgcn_s_setprio(1);                                              \
    acc[0][2] = MFMA16(a00, b20, acc[0][2]); acc[0][2] = MFMA16(a01, b21, acc[0][2]); \
    acc[0][3] = MFMA16(a00, b30, acc[0][3]); acc[0][3] = MFMA16(a01, b31, acc[0][3]); \
    acc[1][2] = MFMA16(a10, b20, acc[1][2]); acc[1][2] = MFMA16(a11, b21, acc[1][2]); \
    acc[1][3] = MFMA16(a10, b30, acc[1][3]); acc[1][3] = MFMA16(a11, b31, acc[1][3]); \
    __builtin_amdgcn_s_setprio(0);                                              \
    __builtin_amdgcn_s_barrier();                                               \
    a00 = rdfrag(lA[d], wm + 32 + llo, lhi16, 0);                               \
    a01 = rdfrag(lA[d], wm + 32 + llo, lhi16, 1);                               \
    a10 = rdfrag(lA[d], wm + 48 + llo, lhi16, 0);                               \
    a11 = rdfrag(lA[d], wm + 48 + llo, lhi16, 1);                               \
    __builtin_amdgcn_s_barrier();                                               \
    asm volatile("s_waitcnt lgkmcnt(0)" ::: "memory");                          \
    __builtin_amdgcn_sched_barrier(0);                                          \
    __builtin_amdgcn_s_setprio(1);                                              \
    acc[2][2] = MFMA16(a00, b20, acc[2][2]); acc[2][2] = MFMA16(a01, b21, acc[2][2]); \
    acc[2][3] = MFMA16(a00, b30, acc[2][3]); acc[2][3] = MFMA16(a01, b31, acc[2][3]); \
    acc[3][2] = MFMA16(a10, b20, acc[3][2]); acc[3][2] = MFMA16(a11, b21, acc[3][2]); \
    acc[3][3] = MFMA16(a10, b30, acc[3][3]); acc[3][3] = MFMA16(a11, b31, acc[3][3]); \
    __builtin_amdgcn_s_setprio(0);                                              \
    __builtin_amdgcn_s_barrier();                                               \
    STAGE6(d, pre_koff);                                                        \
    __builtin_amdgcn_s_barrier();                                               \
    __builtin_amdgcn_s_setprio(1);                                              \
    acc[2][0] = MFMA16(a00, b00, acc[2][0]); acc[2][0] = MFMA16(a01, b01, acc[2][0]); \
    acc[2][1] = MFMA16(a00, b10, acc[2][1]); acc[2][1] = MFMA16(a01, b11, acc[2][1]); \
    acc[3][0] = MFMA16(a10, b00, acc[3][0]); acc[3][0] = MFMA16(a11, b01, acc[3][0]); \
    acc[3][1] = MFMA16(a10, b10, acc[3][1]); acc[3][1] = MFMA16(a11, b11, acc[3][1]); \
    __builtin_amdgcn_s_setprio(0);                                              \
    asm volatile("s_waitcnt vmcnt(6)" ::: "memory");                            \
    __builtin_amdgcn_s_barrier();                                               \
  } while (0)

__device__ __forceinline__ void gemm_core_128x256(
    const u16* __restrict__ A, const u16* __restrict__ Bt,
    int m0, int n0, u16* lds, f32x4 (&acc)[4][4]) {
  const int tid = threadIdx.x;
  const int wid = tid >> 6, lane = tid & 63;
  const int llo = lane & 15, lhi16 = (lane >> 4) * 16;
  const int wm = (wid >> 2) * 64;
  const int wn = (wid & 3) * 64;
  const int K = HIDN;

  const u16* gA[2];
  const u16* gB[4];
#pragma unroll
  for (int q = 0; q < 2; ++q) {
    int off = q * 8192 + tid * 16;
    int s = swz(off);
    gA[q] = A + (size_t)(m0 + (s >> 7)) * K + ((s & 127) >> 1);
  }
#pragma unroll
  for (int q = 0; q < 4; ++q) {
    int off = q * 8192 + tid * 16;
    int s = swz(off);
    gB[q] = Bt + (size_t)(n0 + (s >> 7)) * K + ((s & 127) >> 1);
  }
  u16* lA[2] = { lds, lds + 24576 };
  u16* lB[2] = { lds + 8192, lds + 24576 + 8192 };
  const int wq = wid * 512;

#pragma unroll
  for (int i = 0; i < 4; ++i)
#pragma unroll
    for (int j = 0; j < 4; ++j) acc[i][j] = (f32x4){0.f, 0.f, 0.f, 0.f};

  STAGE6(0, 0);
  STAGE6(1, 64);
  asm volatile("s_waitcnt vmcnt(6)" ::: "memory");
  __builtin_amdgcn_s_barrier();

#pragma unroll 1
  for (int kt = 0; kt < 32; kt += 2) {
    int p0 = (kt + 2 < 32) ? (kt + 2) * 64 : 0;
    int p1 = (kt + 3 < 32) ? (kt + 3) * 64 : 0;
    KTILE(0, p0);
    KTILE(1, p1);
  }
}

// ---------------- QKV GEMM: [4096,2048] x Wt[6144,2048] + bias ---------------
__global__ __launch_bounds__(512, 2) void gemm_qkv8_kernel(
    const u16* __restrict__ A, const u16* __restrict__ Bt,
    const float* __restrict__ bias,
    u16* __restrict__ Qb, u16* __restrict__ Kb, u16* __restrict__ Vt) {
  __shared__ __align__(16) u16 lds[49152];  // 96KB
  int bid = blockIdx.x;
  int sb = (bid & 7) * 96 + (bid >> 3);
  int bx = sb >> 5, by = sb & 31;
  int m0 = by * 128, n0 = bx * 256;

  f32x4 acc[4][4];
  gemm_core_128x256(A, Bt, m0, n0, lds, acc);

  const int tid = threadIdx.x;
  const int wid = tid >> 6, lane = tid & 63;
  const int llo = lane & 15, lhi = lane >> 4;
  const int wm = (wid >> 2) * 64, wn = (wid & 3) * 64;

#pragma unroll
  for (int j = 0; j < 4; ++j) {
    int col = n0 + wn + j * 16 + llo;       // 0..6143
    int h = col / 384;
    int rr = col - h * 384;
    int part = rr >> 7;                     // 0=q 1=k 2=v
    int d = rr & 127;
    float bv = bias[col];
#pragma unroll
    for (int i = 0; i < 4; ++i) {
#pragma unroll
      for (int r = 0; r < 4; ++r) {
        int row = m0 + wm + i * 16 + lhi * 4 + r;  // 0..4095
        int s = row >> 1, b = row & 1;
        int bh = b * NHEAD + h;
        u16 o = f2bf(acc[i][j][r] + bv);
        if (part == 0)      Qb[((size_t)bh * S_LEN + s) * DHEAD + d] = o;
        else if (part == 1) Kb[((size_t)bh * S_LEN + s) * DHEAD + d] = o;
        else                Vt[((size_t)bh * DHEAD + d) * S_LEN + s] = o;
      }
    }
  }
}

// ------------- dense GEMM: ctx[4096,2048] x Wt[2048,2048] -> fp32 out --------
__global__ __launch_bounds__(512, 2) void gemm_dense8_kernel(
    const u16* __restrict__ A, const u16* __restrict__ Bt,
    float* __restrict__ out) {
  __shared__ __align__(16) u16 lds[49152];  // 96KB
  int bid = blockIdx.x;                      // 256 blocks = 32/XCD
  int sb = (bid & 7) * 32 + (bid >> 3);
  int bx = sb >> 5, by = sb & 31;
  int m0 = by * 128, n0 = bx * 256;

  f32x4 acc[4][4];
  gemm_core_128x256(A, Bt, m0, n0, lds, acc);

  const int tid = threadIdx.x;
  const int wid = tid >> 6, lane = tid & 63;
  const int llo = lane & 15, lhi = lane >> 4;
  const int wm = (wid >> 2) * 64, wn = (wid & 3) * 64;

#pragma unroll
  for (int i = 0; i < 4; ++i)
#pragma unroll
    for (int j = 0; j < 4; ++j) {
      int col = n0 + wn + j * 16 + llo;
#pragma unroll
      for (int r = 0; r < 4; ++r) {
        int row = m0 + wm + i * 16 + lhi * 4 + r;
        out[(size_t)row * HIDN + col] = acc[i][j][r];
      }
    }
}

// ---------------- flash attention (causal), one block per (q-tile, bh) -------
// 512 threads = 8 waves x 16 q-rows. K/V staged via global_load_lds into a
// 2x64KB LDS double buffer (zero prefetch VGPRs -- round 5/6's reg-prefetch
// spilled: WRITE_SIZE 203-379MB). Next tile's 8 loads issued BEFORE QK^T,
// drained by vmcnt(0) at tile end (~3-4K cyc later, free). Linear LDS dest +
// pre-swizzled global src + swizzled ds_read (rule #21, byte^=((row&7)<<4))
// replaces the LP pad. P aliases K[cur]; staging targets K[cur^1] (disjoint).
__global__ __launch_bounds__(512, 2) void attn_kernel(
    const u16* __restrict__ Qb, const u16* __restrict__ Kb,
    const u16* __restrict__ Vt, u16* __restrict__ ctx) {
  const int bh = blockIdx.y;   // 0..31
  const int b = bh >> 4, h = bh & 15;
  // balance swizzle: co-resident pairs get qi and 15-qi.
  const int qi = (b == 0) ? blockIdx.x : (15 - blockIdx.x);
  const int tid = threadIdx.x;
  const int wave = tid >> 6, lane = tid & 63;
  const int lhi = lane >> 4, llo = lane & 15;
  __shared__ __align__(16) u16 lds[65536];  // 128KB: 2 x [K 16384 | V 16384] u16

  // staging geometry: thread covers 16B at (row = p*32 + srow, swz byte col scs)
  const int srow = tid >> 4;                                  // 0..31
  const int scs = ((tid & 15) * 16) ^ ((srow & 7) << 4);      // swizzled byte col
  const int sc2 = scs >> 1;                                   // u16 col
  const u16* kbase = Kb + (size_t)bh * S_LEN * DHEAD;
  const u16* vbase = Vt + (size_t)bh * DHEAD * S_LEN;

#define ASTAGE(T, DST) do {                                                        \
    const u16* ks_ = kbase + (size_t)(T) * 128 * DHEAD;                            \
    const u16* vs_ = vbase + (T) * 128;                                            \
    _Pragma("unroll")                                                              \
    for (int p = 0; p < 4; ++p) {                                                  \
      async_cp16(ks_ + (size_t)(p * 32 + srow) * DHEAD + sc2,                      \
                 (DST) + p * 4096 + wave * 512);                                   \
      async_cp16(vs_ + (size_t)(p * 32 + srow) * S_LEN + sc2,                      \
                 (DST) + 16384 + p * 4096 + wave * 512);                           \
    }                                                                              \
  } while (0)

  // ---- Q A-fragments in registers (wave owns 16 q-rows) ----
  bf16x8 aq[4];
  {
    const u16* qsrc = Qb + ((size_t)bh * S_LEN + qi * 128) * DHEAD;
#pragma unroll
    for (int kk = 0; kk < 4; kk++)
      aq[kk] = *(const bf16x8*)&qsrc[(size_t)(wave * 16 + llo) * DHEAD + kk * 32 + lhi * 8];
  }

  f32x4 oacc[8] = {};
  float mrow[4], lrow[4];
#pragma unroll
  for (int r = 0; r < 4; r++) { mrow[r] = -1e30f; lrow[r] = 0.f; }
  const float sc = 0.08838834764831845f;  // 1/sqrt(128)

  // swizzled u16 col for fragment reads: byte (kk*64 + lhi*16) ^ ((llo&7)<<4)
  int bcol[4];
#pragma unroll
  for (int kk = 0; kk < 4; kk++)
    bcol[kk] = ((kk * 64 + lhi * 16) ^ ((llo & 7) << 4)) >> 1;

  // prologue: stage tile 0 into buf 0
  ASTAGE(0, lds);
  asm volatile("s_waitcnt vmcnt(0)" ::: "memory");
  __builtin_amdgcn_s_barrier();
  asm volatile("" ::: "memory");

  for (int kt = 0; kt <= qi; kt++) {
    const int cur = kt & 1;
    u16* Kc = lds + cur * 32768;         // K tile / later P (aliased)
    u16* Vc = Kc + 16384;                // V^T tile [d][t]

    if (kt < qi) ASTAGE(kt + 1, lds + (cur ^ 1) * 32768);  // fly across barriers

    // S = Q K^T  (wave owns 16 q-rows x 128 t-cols)
    f32x4 sacc[8] = {};
    __builtin_amdgcn_s_setprio(1);
#pragma unroll
    for (int kk = 0; kk < 4; kk++) {
#pragma unroll
      for (int j = 0; j < 8; j++) {
        bf16x8 bk = *(const bf16x8*)&Kc[(j * 16 + llo) * 128 + bcol[kk]];
        sacc[j] = MFMA16(aq[kk], bk, sacc[j]);
      }
    }
    __builtin_amdgcn_s_setprio(0);
    asm volatile("" ::: "memory");
    __builtin_amdgcn_s_barrier();   // all waves done reading K (P will alias)
    asm volatile("" ::: "memory");

    if (kt == qi) {  // causal mask on diagonal tile (raw scores)
#pragma unroll
      for (int j = 0; j < 8; j++) {
        int coll = j * 16 + llo;
#pragma unroll
        for (int r = 0; r < 4; r++) {
          int rowl = wave * 16 + lhi * 4 + r;
          if (coll > rowl) sacc[j][r] = -1e30f;
        }
      }
    }

    // online softmax (scale folded into exp); oacc rescale fused in
#pragma unroll
    for (int r = 0; r < 4; r++) {
      float mx = sacc[0][r];
#pragma unroll
      for (int j = 1; j < 8; j++) mx = fmaxf(mx, sacc[j][r]);
#pragma unroll
      for (int off = 1; off < 16; off <<= 1)
        mx = fmaxf(mx, __shfl_xor(mx, off, 64));
      float mnew = fmaxf(mrow[r], mx);
      float al = __expf((mrow[r] - mnew) * sc);
      mrow[r] = mnew;
      float rs = 0.f;
#pragma unroll
      for (int j = 0; j < 8; j++) {
        float e = __expf((sacc[j][r] - mnew) * sc);
        sacc[j][r] = e;
        rs += e;
        oacc[j][r] *= al;
      }
#pragma unroll
      for (int off = 1; off < 16; off <<= 1)
        rs += __shfl_xor(rs, off, 64);
      lrow[r] = lrow[r] * al + rs;
    }

    // P -> LDS over K[cur] (wave-private rows; same-wave order, no barrier)
#pragma unroll
    for (int j = 0; j < 8; j++)
#pragma unroll
      for (int r = 0; r < 4; r++) {
        int pr = wave * 16 + lhi * 4 + r;
        int cb = (j * 16 + llo) * 2;
        Kc[pr * 128 + ((cb ^ ((pr & 7) << 4)) >> 1)] = f2bf(sacc[j][r]);
      }

    // O += P V
    __builtin_amdgcn_s_setprio(1);
#pragma unroll
    for (int kk = 0; kk < 4; kk++) {
      bf16x8 ap = *(const bf16x8*)&Kc[(wave * 16 + llo) * 128 + bcol[kk]];
#pragma unroll
      for (int j = 0; j < 8; j++) {
        bf16x8 bv = *(const bf16x8*)&Vc[(j * 16 + llo) * 128 + bcol[kk]];
        oacc[j] = MFMA16(ap, bv, oacc[j]);
      }
    }
    __builtin_amdgcn_s_setprio(0);

    // staged tile landed (issued ~whole tile ago) + all reads of buf done
    asm volatile("s_waitcnt vmcnt(0)" ::: "memory");
    asm volatile("" ::: "memory");
    __builtin_amdgcn_s_barrier();
    asm volatile("" ::: "memory");
  }
#undef ASTAGE

  // epilogue: O /= l, write ctx[s,b,h*128+d]
  float inv[4];
#pragma unroll
  for (int r = 0; r < 4; r++) inv[r] = 1.f / lrow[r];
#pragma unroll
  for (int j = 0; j < 8; j++) {
    int d = j * 16 + llo;
#pragma unroll
    for (int r = 0; r < 4; r++) {
      int s = qi * 128 + wave * 16 + lhi * 4 + r;
      ctx[((size_t)(s * BATCH + b)) * HIDN + h * DHEAD + d] = f2bf(oacc[j][r] * inv[r]);
    }
  }
}

// ---------------- bias tail: fp32 copy into output slot 1 --------------------
__global__ __launch_bounds__(256) void bias_copy_kernel(
    const float* __restrict__ bsrc, float* __restrict__ dst) {
  int i = blockIdx.x * 256 + threadIdx.x;
  if (i < HIDN) dst[i] = bsrc[i];
}

extern "C" void kernel_launch(void* const* d_in, const int* in_sizes, int n_in,
                              void* d_out, int out_size, void* d_ws, size_t ws_size,
                              hipStream_t stream) {
  int i_hid = 0, i_w1 = 2, i_b1 = 3, i_w2 = 4, i_b2 = 5;
  for (int i = 0; i < n_in; i++) {
    int s = in_sizes[i];
    if (s == MROWS * HIDN)      i_hid = i;
    else if (s == HIDN * NQKV)  i_w1 = i;
    else if (s == NQKV)         i_b1 = i;
    else if (s == HIDN)         i_b2 = i;
  }
  for (int i = n_in - 1; i >= 0; i--)
    if (in_sizes[i] == HIDN * HIDN) { i_w2 = i; break; }

  const float* hidden  = (const float*)d_in[i_hid];
  const float* W_qkv   = (const float*)d_in[i_w1];
  const float* b_qkv   = (const float*)d_in[i_b1];
  const float* W_dense = (const float*)d_in[i_w2];
  const float* b_dense = (const float*)d_in[i_b2];
  float* out = (float*)d_out;

  char* ws = (char*)d_ws;
  u16* Wq_t = (u16*)(ws);
  u16* ctx  = (u16*)(ws);
  u16* Wd_t = (u16*)(ws + 16777216);
  u16* Qb   = (u16*)(ws + 25165824);
  u16* Kb   = (u16*)(ws + 41943040);
  u16* Vt   = (u16*)(ws + 58720256);
  u16* hidden_c = (u16*)d_out;

  convert_hidden_kernel<<<dim3(MROWS * HIDN / 8 / 256), 256, 0, stream>>>(hidden, hidden_c);
  transpose_kernel<<<dim3(NQKV / 64, HIDN / 64), 256, 0, stream>>>(W_qkv, Wq_t, HIDN, NQKV);
  gemm_qkv8_kernel<<<dim3(768), dim3(512), 0, stream>>>(hidden_c, Wq_t, b_qkv, Qb, Kb, Vt);
  attn_kernel<<<dim3(S_LEN / 128, BATCH * NHEAD), dim3(512), 0, stream>>>(Qb, Kb, Vt, ctx);
  transpose_kernel<<<dim3(HIDN / 64, HIDN / 64), 256, 0, stream>>>(W_dense, Wd_t, HIDN, HIDN);
  gemm_dense8_kernel<<<dim3(256), dim3(512), 0, stream>>>(ctx, Wd_t, out);
  bias_copy_kernel<<<dim3(8), 256, 0, stream>>>(b_dense, out + (size_t)MROWS * HIDN);
}

// Round 14
// 443.884 us; speedup vs baseline: 1.2464x; 1.0291x over previous
//
#include <hip/hip_runtime.h>
#include <cstdint>
#include <cstddef>

#define S_LEN 2048
#define BATCH 2
#define HIDN  2048
#define NHEAD 16
#define DHEAD 128
#define NQKV  6144   // 3*NHEAD*DHEAD
#define MROWS 4096   // S_LEN*BATCH

typedef unsigned short u16;
typedef __attribute__((ext_vector_type(8))) __bf16 bf16x8;
typedef __attribute__((ext_vector_type(4))) float f32x4;

__device__ __forceinline__ float bf2f(u16 u) {
  union { uint32_t i; float f; } v; v.i = ((uint32_t)u) << 16; return v.f;
}
__device__ __forceinline__ u16 f2bf(float f) {
  union { float f; uint32_t i; } v; v.f = f;
  uint32_t r = v.i + 0x7fffu + ((v.i >> 16) & 1u);
  return (u16)(r >> 16);
}

__device__ __forceinline__ void async_cp16(const u16* g, u16* l) {
  __builtin_amdgcn_global_load_lds(
      (const __attribute__((address_space(1))) void*)g,
      (__attribute__((address_space(3))) void*)l, 16, 0, 0);
}

// ---------------- hidden canonicalize: fp32[N] -> bf16[N] --------------------
__global__ __launch_bounds__(256) void convert_hidden_kernel(
    const float* __restrict__ src, u16* __restrict__ out) {
  size_t c = (size_t)blockIdx.x * 256 + threadIdx.x;  // chunk of 8 elements
  const float4* in = (const float4*)(src + c * 8);
  float4 v0 = in[0], v1 = in[1];
  u16 t[8] = {f2bf(v0.x), f2bf(v0.y), f2bf(v0.z), f2bf(v0.w),
              f2bf(v1.x), f2bf(v1.y), f2bf(v1.z), f2bf(v1.w)};
  *(uint4*)&out[c * 8] = *(const uint4*)t;
}

// ---------------- transpose+cast: fp32 in[R][C] -> bf16 out[C][R] ------------
__global__ __launch_bounds__(256) void transpose_kernel(
    const float* __restrict__ in, u16* __restrict__ out, int R, int C) {
  __shared__ u16 tile[64][72];
  const int bx = blockIdx.x * 64;  // col base in `in`
  const int by = blockIdx.y * 64;  // row base in `in`
  const int lx = threadIdx.x & 15, ly = threadIdx.x >> 4;
#pragma unroll
  for (int i = 0; i < 4; i++) {
    int r = ly * 4 + i;
    float4 v = *(const float4*)&in[(size_t)(by + r) * C + bx + lx * 4];
    tile[r][lx * 4 + 0] = f2bf(v.x); tile[r][lx * 4 + 1] = f2bf(v.y);
    tile[r][lx * 4 + 2] = f2bf(v.z); tile[r][lx * 4 + 3] = f2bf(v.w);
  }
  __syncthreads();
#pragma unroll
  for (int i = 0; i < 4; i++) {
    int oc = ly * 4 + i;  // out row = bx + oc
    ushort4 o;
    o.x = tile[lx * 4 + 0][oc]; o.y = tile[lx * 4 + 1][oc];
    o.z = tile[lx * 4 + 2][oc]; o.w = tile[lx * 4 + 3][oc];
    *(ushort4*)&out[(size_t)(bx + oc) * R + by + lx * 4] = o;
  }
}

// =============================================================================
// 2-phase 128x256 GEMM core. Round-8 PM: the 4-phase/9-barrier KTILE gave
// 3.6 MFMA/barrier -> MfmaUtil 28%, sync-bound. Now: ALL 16 fragment reads up
// front, 3 barriers/K-tile, 16 MFMA per phase (10.7 MFMA/barrier).
//   B1 after reads; lgkmcnt(0); 16 MFMA (quadrants 0,1); B2 (arch-guarantees
//   all waves' buf-d reads done: each wave's lgkm preceded it); STAGE6 (tile
//   t+2, same buf -- WAR-safe); 16 MFMA (quadrants 2,3, reg-only);
//   vmcnt(6) (waits t+1's loads, issued one full K-tile ago); B3.
// Swizzle unchanged (2-way residual); vmcnt never 0 in loop.
// =============================================================================

__device__ __forceinline__ int swz(int o) {
  return o ^ ((o >> 3) & 16) ^ ((o >> 4) & 0x60);
}

__device__ __forceinline__ bf16x8 rdfrag(const u16* ldsT, int row, int lhi16, int kk) {
  int off = row * 128 + kk * 64 + lhi16;
  off ^= ((off >> 3) & 16) ^ ((off >> 4) & 0x60);
  return *(const bf16x8*)((const char*)ldsT + off);
}

#define MFMA16(a, b, c) __builtin_amdgcn_mfma_f32_16x16x32_bf16(a, b, c, 0, 0, 0)

#define STAGE6(d, koff) do {                                  \
    async_cp16(gA[0] + (koff), lA[d] + wq);                   \
    async_cp16(gA[1] + (koff), lA[d] + 4096 + wq);            \
    async_cp16(gB[0] + (koff), lB[d] + wq);                   \
    async_cp16(gB[1] + (koff), lB[d] + 4096 + wq);            \
    async_cp16(gB[2] + (koff), lB[d] + 8192 + wq);            \
    async_cp16(gB[3] + (koff), lB[d] + 12288 + wq);           \
  } while (0)

#define KTILE(d, pre_koff) do {                                                 \
    bf16x8 a00, a01, a10, a11, a20, a21, a30, a31;                              \
    bf16x8 b00, b01, b10, b11, b20, b21, b30, b31;                              \
    a00 = rdfrag(lA[d], wm + llo,      lhi16, 0);                               \
    a01 = rdfrag(lA[d], wm + llo,      lhi16, 1);                               \
    a10 = rdfrag(lA[d], wm + 16 + llo, lhi16, 0);                               \
    a11 = rdfrag(lA[d], wm + 16 + llo, lhi16, 1);                               \
    a20 = rdfrag(lA[d], wm + 32 + llo, lhi16, 0);                               \
    a21 = rdfrag(lA[d], wm + 32 + llo, lhi16, 1);                               \
    a30 = rdfrag(lA[d], wm + 48 + llo, lhi16, 0);                               \
    a31 = rdfrag(lA[d], wm + 48 + llo, lhi16, 1);                               \
    b00 = rdfrag(lB[d], wn + llo,      lhi16, 0);                               \
    b01 = rdfrag(lB[d], wn + llo,      lhi16, 1);                               \
    b10 = rdfrag(lB[d], wn + 16 + llo, lhi16, 0);                               \
    b11 = rdfrag(lB[d], wn + 16 + llo, lhi16, 1);                               \
    b20 = rdfrag(lB[d], wn + 32 + llo, lhi16, 0);                               \
    b21 = rdfrag(lB[d], wn + 32 + llo, lhi16, 1);                               \
    b30 = rdfrag(lB[d], wn + 48 + llo, lhi16, 0);                               \
    b31 = rdfrag(lB[d], wn + 48 + llo, lhi16, 1);                               \
    __builtin_amdgcn_s_barrier();                                               \
    asm volatile("s_waitcnt lgkmcnt(0)" ::: "memory");                          \
    __builtin_amdgcn_sched_barrier(0);                                          \
    __builtin_amdgcn_s_setprio(1);                                              \
    acc[0][0] = MFMA16(a00, b00, acc[0][0]); acc[0][0] = MFMA16(a01, b01, acc[0][0]); \
    acc[0][1] = MFMA16(a00, b10, acc[0][1]); acc[0][1] = MFMA16(a01, b11, acc[0][1]); \
    acc[0][2] = MFMA16(a00, b20, acc[0][2]); acc[0][2] = MFMA16(a01, b21, acc[0][2]); \
    acc[0][3] = MFMA16(a00, b30, acc[0][3]); acc[0][3] = MFMA16(a01, b31, acc[0][3]); \
    acc[1][0] = MFMA16(a10, b00, acc[1][0]); acc[1][0] = MFMA16(a11, b01, acc[1][0]); \
    acc[1][1] = MFMA16(a10, b10, acc[1][1]); acc[1][1] = MFMA16(a11, b11, acc[1][1]); \
    acc[1][2] = MFMA16(a10, b20, acc[1][2]); acc[1][2] = MFMA16(a11, b21, acc[1][2]); \
    acc[1][3] = MFMA16(a10, b30, acc[1][3]); acc[1][3] = MFMA16(a11, b31, acc[1][3]); \
    __builtin_amdgcn_s_setprio(0);                                              \
    __builtin_amdgcn_s_barrier();  /* all buf-d reads complete chip-wide */     \
    STAGE6(d, pre_koff);                                                        \
    __builtin_amdgcn_s_setprio(1);                                              \
    acc[2][0] = MFMA16(a20, b00, acc[2][0]); acc[2][0] = MFMA16(a21, b01, acc[2][0]); \
    acc[2][1] = MFMA16(a20, b10, acc[2][1]); acc[2][1] = MFMA16(a21, b11, acc[2][1]); \
    acc[2][2] = MFMA16(a20, b20, acc[2][2]); acc[2][2] = MFMA16(a21, b21, acc[2][2]); \
    acc[2][3] = MFMA16(a20, b30, acc[2][3]); acc[2][3] = MFMA16(a21, b31, acc[2][3]); \
    acc[3][0] = MFMA16(a30, b00, acc[3][0]); acc[3][0] = MFMA16(a31, b01, acc[3][0]); \
    acc[3][1] = MFMA16(a30, b10, acc[3][1]); acc[3][1] = MFMA16(a31, b11, acc[3][1]); \
    acc[3][2] = MFMA16(a30, b20, acc[3][2]); acc[3][2] = MFMA16(a31, b21, acc[3][2]); \
    acc[3][3] = MFMA16(a30, b30, acc[3][3]); acc[3][3] = MFMA16(a31, b31, acc[3][3]); \
    __builtin_amdgcn_s_setprio(0);                                              \
    asm volatile("s_waitcnt vmcnt(6)" ::: "memory");                            \
    __builtin_amdgcn_s_barrier();                                               \
  } while (0)

__device__ __forceinline__ void gemm_core_128x256(
    const u16* __restrict__ A, const u16* __restrict__ Bt,
    int m0, int n0, u16* lds, f32x4 (&acc)[4][4]) {
  const int tid = threadIdx.x;
  const int wid = tid >> 6, lane = tid & 63;
  const int llo = lane & 15, lhi16 = (lane >> 4) * 16;
  const int wm = (wid >> 2) * 64;
  const int wn = (wid & 3) * 64;
  const int K = HIDN;

  const u16* gA[2];
  const u16* gB[4];
#pragma unroll
  for (int q = 0; q < 2; ++q) {
    int off = q * 8192 + tid * 16;
    int s = swz(off);
    gA[q] = A + (size_t)(m0 + (s >> 7)) * K + ((s & 127) >> 1);
  }
#pragma unroll
  for (int q = 0; q < 4; ++q) {
    int off = q * 8192 + tid * 16;
    int s = swz(off);
    gB[q] = Bt + (size_t)(n0 + (s >> 7)) * K + ((s & 127) >> 1);
  }
  u16* lA[2] = { lds, lds + 24576 };
  u16* lB[2] = { lds + 8192, lds + 24576 + 8192 };
  const int wq = wid * 512;

#pragma unroll
  for (int i = 0; i < 4; ++i)
#pragma unroll
    for (int j = 0; j < 4; ++j) acc[i][j] = (f32x4){0.f, 0.f, 0.f, 0.f};

  STAGE6(0, 0);
  STAGE6(1, 64);
  asm volatile("s_waitcnt vmcnt(6)" ::: "memory");
  __builtin_amdgcn_s_barrier();

#pragma unroll 1
  for (int kt = 0; kt < 32; kt += 2) {
    int p0 = (kt + 2 < 32) ? (kt + 2) * 64 : 0;
    int p1 = (kt + 3 < 32) ? (kt + 3) * 64 : 0;
    KTILE(0, p0);
    KTILE(1, p1);
  }
}

// ---------------- QKV GEMM: [4096,2048] x Wt[6144,2048] + bias ---------------
// XCD map (round-8 PM: bx-major streamed 16MB of A through each 4MB L2,
// FETCH 211MB): partition BY across XCDs -- XCD x owns by in [4x,4x+4),
// bx streams; hot A per XCD <= 1MB (L2-fits), B served from L3.
__global__ __launch_bounds__(512, 2) void gemm_qkv8_kernel(
    const u16* __restrict__ A, const u16* __restrict__ Bt,
    const float* __restrict__ bias,
    u16* __restrict__ Qb, u16* __restrict__ Kb, u16* __restrict__ Vt) {
  __shared__ __align__(16) u16 lds[49152];  // 96KB
  int bid = blockIdx.x;                 // 768 = 8 XCD x 4 by x 24 bx
  int x = bid & 7, s = bid >> 3;        // s in 0..95
  int by = x * 4 + s / 24;
  int bx = s % 24;
  int m0 = by * 128, n0 = bx * 256;

  f32x4 acc[4][4];
  gemm_core_128x256(A, Bt, m0, n0, lds, acc);

  const int tid = threadIdx.x;
  const int wid = tid >> 6, lane = tid & 63;
  const int llo = lane & 15, lhi = lane >> 4;
  const int wm = (wid >> 2) * 64, wn = (wid & 3) * 64;

#pragma unroll
  for (int j = 0; j < 4; ++j) {
    int col = n0 + wn + j * 16 + llo;       // 0..6143
    int h = col / 384;
    int rr = col - h * 384;
    int part = rr >> 7;                     // 0=q 1=k 2=v
    int d = rr & 127;
    float bv = bias[col];
#pragma unroll
    for (int i = 0; i < 4; ++i) {
#pragma unroll
      for (int r = 0; r < 4; ++r) {
        int row = m0 + wm + i * 16 + lhi * 4 + r;  // 0..4095
        int s2 = row >> 1, b = row & 1;
        int bh = b * NHEAD + h;
        u16 o = f2bf(acc[i][j][r] + bv);
        if (part == 0)      Qb[((size_t)bh * S_LEN + s2) * DHEAD + d] = o;
        else if (part == 1) Kb[((size_t)bh * S_LEN + s2) * DHEAD + d] = o;
        else                Vt[((size_t)bh * DHEAD + d) * S_LEN + s2] = o;
      }
    }
  }
}

// ------------- dense GEMM: ctx[4096,2048] x Wt[2048,2048] -> fp32 out --------
__global__ __launch_bounds__(512, 2) void gemm_dense8_kernel(
    const u16* __restrict__ A, const u16* __restrict__ Bt,
    float* __restrict__ out) {
  __shared__ __align__(16) u16 lds[49152];  // 96KB
  int bid = blockIdx.x;                 // 256 = 8 XCD x 4 by x 8 bx
  int x = bid & 7, s = bid >> 3;        // s in 0..31
  int by = x * 4 + s / 8;
  int bx = s % 8;
  int m0 = by * 128, n0 = bx * 256;

  f32x4 acc[4][4];
  gemm_core_128x256(A, Bt, m0, n0, lds, acc);

  const int tid = threadIdx.x;
  const int wid = tid >> 6, lane = tid & 63;
  const int llo = lane & 15, lhi = lane >> 4;
  const int wm = (wid >> 2) * 64, wn = (wid & 3) * 64;

#pragma unroll
  for (int i = 0; i < 4; ++i)
#pragma unroll
    for (int j = 0; j < 4; ++j) {
      int col = n0 + wn + j * 16 + llo;
#pragma unroll
      for (int r = 0; r < 4; ++r) {
        int row = m0 + wm + i * 16 + lhi * 4 + r;
        out[(size_t)row * HIDN + col] = acc[i][j][r];
      }
    }
}

// ---------------- flash attention (causal), one block per (q-tile, bh) -------
// (unchanged from round 8 -- passed; global_load_lds double-buffer, no spill)
__global__ __launch_bounds__(512, 2) void attn_kernel(
    const u16* __restrict__ Qb, const u16* __restrict__ Kb,
    const u16* __restrict__ Vt, u16* __restrict__ ctx) {
  const int bh = blockIdx.y;   // 0..31
  const int b = bh >> 4, h = bh & 15;
  const int qi = (b == 0) ? blockIdx.x : (15 - blockIdx.x);
  const int tid = threadIdx.x;
  const int wave = tid >> 6, lane = tid & 63;
  const int lhi = lane >> 4, llo = lane & 15;
  __shared__ __align__(16) u16 lds[65536];  // 128KB: 2 x [K 16384 | V 16384] u16

  const int srow = tid >> 4;                                  // 0..31
  const int scs = ((tid & 15) * 16) ^ ((srow & 7) << 4);      // swizzled byte col
  const int sc2 = scs >> 1;                                   // u16 col
  const u16* kbase = Kb + (size_t)bh * S_LEN * DHEAD;
  const u16* vbase = Vt + (size_t)bh * DHEAD * S_LEN;

#define ASTAGE(T, DST) do {                                                        \
    const u16* ks_ = kbase + (size_t)(T) * 128 * DHEAD;                            \
    const u16* vs_ = vbase + (T) * 128;                                            \
    _Pragma("unroll")                                                              \
    for (int p = 0; p < 4; ++p) {                                                  \
      async_cp16(ks_ + (size_t)(p * 32 + srow) * DHEAD + sc2,                      \
                 (DST) + p * 4096 + wave * 512);                                   \
      async_cp16(vs_ + (size_t)(p * 32 + srow) * S_LEN + sc2,                      \
                 (DST) + 16384 + p * 4096 + wave * 512);                           \
    }                                                                              \
  } while (0)

  bf16x8 aq[4];
  {
    const u16* qsrc = Qb + ((size_t)bh * S_LEN + qi * 128) * DHEAD;
#pragma unroll
    for (int kk = 0; kk < 4; kk++)
      aq[kk] = *(const bf16x8*)&qsrc[(size_t)(wave * 16 + llo) * DHEAD + kk * 32 + lhi * 8];
  }

  f32x4 oacc[8] = {};
  float mrow[4], lrow[4];
#pragma unroll
  for (int r = 0; r < 4; r++) { mrow[r] = -1e30f; lrow[r] = 0.f; }
  const float sc = 0.08838834764831845f;  // 1/sqrt(128)

  int bcol[4];
#pragma unroll
  for (int kk = 0; kk < 4; kk++)
    bcol[kk] = ((kk * 64 + lhi * 16) ^ ((llo & 7) << 4)) >> 1;

  ASTAGE(0, lds);
  asm volatile("s_waitcnt vmcnt(0)" ::: "memory");
  __builtin_amdgcn_s_barrier();
  asm volatile("" ::: "memory");

  for (int kt = 0; kt <= qi; kt++) {
    const int cur = kt & 1;
    u16* Kc = lds + cur * 32768;         // K tile / later P (aliased)
    u16* Vc = Kc + 16384;                // V^T tile [d][t]

    if (kt < qi) ASTAGE(kt + 1, lds + (cur ^ 1) * 32768);

    f32x4 sacc[8] = {};
    __builtin_amdgcn_s_setprio(1);
#pragma unroll
    for (int kk = 0; kk < 4; kk++) {
#pragma unroll
      for (int j = 0; j < 8; j++) {
        bf16x8 bk = *(const bf16x8*)&Kc[(j * 16 + llo) * 128 + bcol[kk]];
        sacc[j] = MFMA16(aq[kk], bk, sacc[j]);
      }
    }
    __builtin_amdgcn_s_setprio(0);
    asm volatile("" ::: "memory");
    __builtin_amdgcn_s_barrier();
    asm volatile("" ::: "memory");

    if (kt == qi) {
#pragma unroll
      for (int j = 0; j < 8; j++) {
        int coll = j * 16 + llo;
#pragma unroll
        for (int r = 0; r < 4; r++) {
          int rowl = wave * 16 + lhi * 4 + r;
          if (coll > rowl) sacc[j][r] = -1e30f;
        }
      }
    }

#pragma unroll
    for (int r = 0; r < 4; r++) {
      float mx = sacc[0][r];
#pragma unroll
      for (int j = 1; j < 8; j++) mx = fmaxf(mx, sacc[j][r]);
#pragma unroll
      for (int off = 1; off < 16; off <<= 1)
        mx = fmaxf(mx, __shfl_xor(mx, off, 64));
      float mnew = fmaxf(mrow[r], mx);
      float al = __expf((mrow[r] - mnew) * sc);
      mrow[r] = mnew;
      float rs = 0.f;
#pragma unroll
      for (int j = 0; j < 8; j++) {
        float e = __expf((sacc[j][r] - mnew) * sc);
        sacc[j][r] = e;
        rs += e;
        oacc[j][r] *= al;
      }
#pragma unroll
      for (int off = 1; off < 16; off <<= 1)
        rs += __shfl_xor(rs, off, 64);
      lrow[r] = lrow[r] * al + rs;
    }

#pragma unroll
    for (int j = 0; j < 8; j++)
#pragma unroll
      for (int r = 0; r < 4; r++) {
        int pr = wave * 16 + lhi * 4 + r;
        int cb = (j * 16 + llo) * 2;
        Kc[pr * 128 + ((cb ^ ((pr & 7) << 4)) >> 1)] = f2bf(sacc[j][r]);
      }

    __builtin_amdgcn_s_setprio(1);
#pragma unroll
    for (int kk = 0; kk < 4; kk++) {
      bf16x8 ap = *(const bf16x8*)&Kc[(wave * 16 + llo) * 128 + bcol[kk]];
#pragma unroll
      for (int j = 0; j < 8; j++) {
        bf16x8 bv = *(const bf16x8*)&Vc[(j * 16 + llo) * 128 + bcol[kk]];
        oacc[j] = MFMA16(ap, bv, oacc[j]);
      }
    }
    __builtin_amdgcn_s_setprio(0);

    asm volatile("s_waitcnt vmcnt(0)" ::: "memory");
    asm volatile("" ::: "memory");
    __builtin_amdgcn_s_barrier();
    asm volatile("" ::: "memory");
  }
#undef ASTAGE

  float inv[4];
#pragma unroll
  for (int r = 0; r < 4; r++) inv[r] = 1.f / lrow[r];
#pragma unroll
  for (int j = 0; j < 8; j++) {
    int d = j * 16 + llo;
#pragma unroll
    for (int r = 0; r < 4; r++) {
      int s = qi * 128 + wave * 16 + lhi * 4 + r;
      ctx[((size_t)(s * BATCH + b)) * HIDN + h * DHEAD + d] = f2bf(oacc[j][r] * inv[r]);
    }
  }
}

// ---------------- bias tail: fp32 copy into output slot 1 --------------------
__global__ __launch_bounds__(256) void bias_copy_kernel(
    const float* __restrict__ bsrc, float* __restrict__ dst) {
  int i = blockIdx.x * 256 + threadIdx.x;
  if (i < HIDN) dst[i] = bsrc[i];
}

extern "C" void kernel_launch(void* const* d_in, const int* in_sizes, int n_in,
                              void* d_out, int out_size, void* d_ws, size_t ws_size,
                              hipStream_t stream) {
  int i_hid = 0, i_w1 = 2, i_b1 = 3, i_w2 = 4, i_b2 = 5;
  for (int i = 0; i < n_in; i++) {
    int s = in_sizes[i];
    if (s == MROWS * HIDN)      i_hid = i;
    else if (s == HIDN * NQKV)  i_w1 = i;
    else if (s == NQKV)         i_b1 = i;
    else if (s == HIDN)         i_b2 = i;
  }
  for (int i = n_in - 1; i >= 0; i--)
    if (in_sizes[i] == HIDN * HIDN) { i_w2 = i; break; }

  const float* hidden  = (const float*)d_in[i_hid];
  const float* W_qkv   = (const float*)d_in[i_w1];
  const float* b_qkv   = (const float*)d_in[i_b1];
  const float* W_dense = (const float*)d_in[i_w2];
  const float* b_dense = (const float*)d_in[i_b2];
  float* out = (float*)d_out;

  char* ws = (char*)d_ws;
  u16* Wq_t = (u16*)(ws);
  u16* ctx  = (u16*)(ws);
  u16* Wd_t = (u16*)(ws + 16777216);
  u16* Qb   = (u16*)(ws + 25165824);
  u16* Kb   = (u16*)(ws + 41943040);
  u16* Vt   = (u16*)(ws + 58720256);
  u16* hidden_c = (u16*)d_out;

  convert_hidden_kernel<<<dim3(MROWS * HIDN / 8 / 256), 256, 0, stream>>>(hidden, hidden_c);
  transpose_kernel<<<dim3(NQKV / 64, HIDN / 64), 256, 0, stream>>>(W_qkv, Wq_t, HIDN, NQKV);
  gemm_qkv8_kernel<<<dim3(768), dim3(512), 0, stream>>>(hidden_c, Wq_t, b_qkv, Qb, Kb, Vt);
  attn_kernel<<<dim3(S_LEN / 128, BATCH * NHEAD), dim3(512), 0, stream>>>(Qb, Kb, Vt, ctx);
  transpose_kernel<<<dim3(HIDN / 64, HIDN / 64), 256, 0, stream>>>(W_dense, Wd_t, HIDN, HIDN);
  gemm_dense8_kernel<<<dim3(256), dim3(512), 0, stream>>>(ctx, Wd_t, out);
  bias_copy_kernel<<<dim3(8), 256, 0, stream>>>(b_dense, out + (size_t)MROWS * HIDN);
}

// Round 15
// 441.367 us; speedup vs baseline: 1.2535x; 1.0057x over previous
//
#include <hip/hip_runtime.h>
#include <cstdint>
#include <cstddef>

#define S_LEN 2048
#define BATCH 2
#define HIDN  2048
#define NHEAD 16
#define DHEAD 128
#define NQKV  6144   // 3*NHEAD*DHEAD
#define MROWS 4096   // S_LEN*BATCH

typedef unsigned short u16;
typedef __attribute__((ext_vector_type(8))) __bf16 bf16x8;
typedef __attribute__((ext_vector_type(4))) float f32x4;

__device__ __forceinline__ float bf2f(u16 u) {
  union { uint32_t i; float f; } v; v.i = ((uint32_t)u) << 16; return v.f;
}
__device__ __forceinline__ u16 f2bf(float f) {
  union { float f; uint32_t i; } v; v.f = f;
  uint32_t r = v.i + 0x7fffu + ((v.i >> 16) & 1u);
  return (u16)(r >> 16);
}

__device__ __forceinline__ void async_cp16(const u16* g, u16* l) {
  __builtin_amdgcn_global_load_lds(
      (const __attribute__((address_space(1))) void*)g,
      (__attribute__((address_space(3))) void*)l, 16, 0, 0);
}

// ---------------- hidden canonicalize: fp32[N] -> bf16[N] --------------------
__global__ __launch_bounds__(256) void convert_hidden_kernel(
    const float* __restrict__ src, u16* __restrict__ out) {
  size_t c = (size_t)blockIdx.x * 256 + threadIdx.x;  // chunk of 8 elements
  const float4* in = (const float4*)(src + c * 8);
  float4 v0 = in[0], v1 = in[1];
  u16 t[8] = {f2bf(v0.x), f2bf(v0.y), f2bf(v0.z), f2bf(v0.w),
              f2bf(v1.x), f2bf(v1.y), f2bf(v1.z), f2bf(v1.w)};
  *(uint4*)&out[c * 8] = *(const uint4*)t;
}

// ---------------- transpose+cast: fp32 in[R][C] -> bf16 out[C][R] ------------
__global__ __launch_bounds__(256) void transpose_kernel(
    const float* __restrict__ in, u16* __restrict__ out, int R, int C) {
  __shared__ u16 tile[64][72];
  const int bx = blockIdx.x * 64;  // col base in `in`
  const int by = blockIdx.y * 64;  // row base in `in`
  const int lx = threadIdx.x & 15, ly = threadIdx.x >> 4;
#pragma unroll
  for (int i = 0; i < 4; i++) {
    int r = ly * 4 + i;
    float4 v = *(const float4*)&in[(size_t)(by + r) * C + bx + lx * 4];
    tile[r][lx * 4 + 0] = f2bf(v.x); tile[r][lx * 4 + 1] = f2bf(v.y);
    tile[r][lx * 4 + 2] = f2bf(v.z); tile[r][lx * 4 + 3] = f2bf(v.w);
  }
  __syncthreads();
#pragma unroll
  for (int i = 0; i < 4; i++) {
    int oc = ly * 4 + i;  // out row = bx + oc
    ushort4 o;
    o.x = tile[lx * 4 + 0][oc]; o.y = tile[lx * 4 + 1][oc];
    o.z = tile[lx * 4 + 2][oc]; o.w = tile[lx * 4 + 3][oc];
    *(ushort4*)&out[(size_t)(bx + oc) * R + by + lx * 4] = o;
  }
}

// =============================================================================
// 2-phase 128x256 GEMM core, BK=64 (3 barriers/K-tile, 10.7 MFMA/barrier).
// Round-14 PM: 2-phase alone was ~neutral (152 vs 155us; MfmaUtil 29%) because
// the round-14 by-partition XCD map REGRESSED fetch (211->315MB, streaming B
// through L2 instead of A) and made staging the critical path (~3790cyc/KTILE
// at 10B/cyc/CU effective). This round: revert to the round-8 empirically-best
// map (share B within XCD, stream A) to isolate the 2-phase benefit.
// =============================================================================

__device__ __forceinline__ int swz(int o) {
  return o ^ ((o >> 3) & 16) ^ ((o >> 4) & 0x60);
}

__device__ __forceinline__ bf16x8 rdfrag(const u16* ldsT, int row, int lhi16, int kk) {
  int off = row * 128 + kk * 64 + lhi16;
  off ^= ((off >> 3) & 16) ^ ((off >> 4) & 0x60);
  return *(const bf16x8*)((const char*)ldsT + off);
}

#define MFMA16(a, b, c) __builtin_amdgcn_mfma_f32_16x16x32_bf16(a, b, c, 0, 0, 0)

#define STAGE6(d, koff) do {                                  \
    async_cp16(gA[0] + (koff), lA[d] + wq);                   \
    async_cp16(gA[1] + (koff), lA[d] + 4096 + wq);            \
    async_cp16(gB[0] + (koff), lB[d] + wq);                   \
    async_cp16(gB[1] + (koff), lB[d] + 4096 + wq);            \
    async_cp16(gB[2] + (koff), lB[d] + 8192 + wq);            \
    async_cp16(gB[3] + (koff), lB[d] + 12288 + wq);           \
  } while (0)

#define KTILE(d, pre_koff) do {                                                 \
    bf16x8 a00, a01, a10, a11, a20, a21, a30, a31;                              \
    bf16x8 b00, b01, b10, b11, b20, b21, b30, b31;                              \
    a00 = rdfrag(lA[d], wm + llo,      lhi16, 0);                               \
    a01 = rdfrag(lA[d], wm + llo,      lhi16, 1);                               \
    a10 = rdfrag(lA[d], wm + 16 + llo, lhi16, 0);                               \
    a11 = rdfrag(lA[d], wm + 16 + llo, lhi16, 1);                               \
    a20 = rdfrag(lA[d], wm + 32 + llo, lhi16, 0);                               \
    a21 = rdfrag(lA[d], wm + 32 + llo, lhi16, 1);                               \
    a30 = rdfrag(lA[d], wm + 48 + llo, lhi16, 0);                               \
    a31 = rdfrag(lA[d], wm + 48 + llo, lhi16, 1);                               \
    b00 = rdfrag(lB[d], wn + llo,      lhi16, 0);                               \
    b01 = rdfrag(lB[d], wn + llo,      lhi16, 1);                               \
    b10 = rdfrag(lB[d], wn + 16 + llo, lhi16, 0);                               \
    b11 = rdfrag(lB[d], wn + 16 + llo, lhi16, 1);                               \
    b20 = rdfrag(lB[d], wn + 32 + llo, lhi16, 0);                               \
    b21 = rdfrag(lB[d], wn + 32 + llo, lhi16, 1);                               \
    b30 = rdfrag(lB[d], wn + 48 + llo, lhi16, 0);                               \
    b31 = rdfrag(lB[d], wn + 48 + llo, lhi16, 1);                               \
    __builtin_amdgcn_s_barrier();                                               \
    asm volatile("s_waitcnt lgkmcnt(0)" ::: "memory");                          \
    __builtin_amdgcn_sched_barrier(0);                                          \
    __builtin_amdgcn_s_setprio(1);                                              \
    acc[0][0] = MFMA16(a00, b00, acc[0][0]); acc[0][0] = MFMA16(a01, b01, acc[0][0]); \
    acc[0][1] = MFMA16(a00, b10, acc[0][1]); acc[0][1] = MFMA16(a01, b11, acc[0][1]); \
    acc[0][2] = MFMA16(a00, b20, acc[0][2]); acc[0][2] = MFMA16(a01, b21, acc[0][2]); \
    acc[0][3] = MFMA16(a00, b30, acc[0][3]); acc[0][3] = MFMA16(a01, b31, acc[0][3]); \
    acc[1][0] = MFMA16(a10, b00, acc[1][0]); acc[1][0] = MFMA16(a11, b01, acc[1][0]); \
    acc[1][1] = MFMA16(a10, b10, acc[1][1]); acc[1][1] = MFMA16(a11, b11, acc[1][1]); \
    acc[1][2] = MFMA16(a10, b20, acc[1][2]); acc[1][2] = MFMA16(a11, b21, acc[1][2]); \
    acc[1][3] = MFMA16(a10, b30, acc[1][3]); acc[1][3] = MFMA16(a11, b31, acc[1][3]); \
    __builtin_amdgcn_s_setprio(0);                                              \
    __builtin_amdgcn_s_barrier();  /* all buf-d reads complete chip-wide */     \
    STAGE6(d, pre_koff);                                                        \
    __builtin_amdgcn_s_setprio(1);                                              \
    acc[2][0] = MFMA16(a20, b00, acc[2][0]); acc[2][0] = MFMA16(a21, b01, acc[2][0]); \
    acc[2][1] = MFMA16(a20, b10, acc[2][1]); acc[2][1] = MFMA16(a21, b11, acc[2][1]); \
    acc[2][2] = MFMA16(a20, b20, acc[2][2]); acc[2][2] = MFMA16(a21, b21, acc[2][2]); \
    acc[2][3] = MFMA16(a20, b30, acc[2][3]); acc[2][3] = MFMA16(a21, b31, acc[2][3]); \
    acc[3][0] = MFMA16(a30, b00, acc[3][0]); acc[3][0] = MFMA16(a31, b01, acc[3][0]); \
    acc[3][1] = MFMA16(a30, b10, acc[3][1]); acc[3][1] = MFMA16(a31, b11, acc[3][1]); \
    acc[3][2] = MFMA16(a30, b20, acc[3][2]); acc[3][2] = MFMA16(a31, b21, acc[3][2]); \
    acc[3][3] = MFMA16(a30, b30, acc[3][3]); acc[3][3] = MFMA16(a31, b31, acc[3][3]); \
    __builtin_amdgcn_s_setprio(0);                                              \
    asm volatile("s_waitcnt vmcnt(6)" ::: "memory");                            \
    __builtin_amdgcn_s_barrier();                                               \
  } while (0)

__device__ __forceinline__ void gemm_core_128x256(
    const u16* __restrict__ A, const u16* __restrict__ Bt,
    int m0, int n0, u16* lds, f32x4 (&acc)[4][4]) {
  const int tid = threadIdx.x;
  const int wid = tid >> 6, lane = tid & 63;
  const int llo = lane & 15, lhi16 = (lane >> 4) * 16;
  const int wm = (wid >> 2) * 64;
  const int wn = (wid & 3) * 64;
  const int K = HIDN;

  const u16* gA[2];
  const u16* gB[4];
#pragma unroll
  for (int q = 0; q < 2; ++q) {
    int off = q * 8192 + tid * 16;
    int s = swz(off);
    gA[q] = A + (size_t)(m0 + (s >> 7)) * K + ((s & 127) >> 1);
  }
#pragma unroll
  for (int q = 0; q < 4; ++q) {
    int off = q * 8192 + tid * 16;
    int s = swz(off);
    gB[q] = Bt + (size_t)(n0 + (s >> 7)) * K + ((s & 127) >> 1);
  }
  u16* lA[2] = { lds, lds + 24576 };
  u16* lB[2] = { lds + 8192, lds + 24576 + 8192 };
  const int wq = wid * 512;

#pragma unroll
  for (int i = 0; i < 4; ++i)
#pragma unroll
    for (int j = 0; j < 4; ++j) acc[i][j] = (f32x4){0.f, 0.f, 0.f, 0.f};

  STAGE6(0, 0);
  STAGE6(1, 64);
  asm volatile("s_waitcnt vmcnt(6)" ::: "memory");
  __builtin_amdgcn_s_barrier();

#pragma unroll 1
  for (int kt = 0; kt < 32; kt += 2) {
    int p0 = (kt + 2 < 32) ? (kt + 2) * 64 : 0;
    int p1 = (kt + 3 < 32) ? (kt + 3) * 64 : 0;
    KTILE(0, p0);
    KTILE(1, p1);
  }
}

// ---------------- QKV GEMM: [4096,2048] x Wt[6144,2048] + bias ---------------
// XCD map: round-8 empirical best (FETCH 211MB vs round-14's 315MB).
// Consecutive blocks on an XCD share the B panel (bx) and sweep by.
__global__ __launch_bounds__(512, 2) void gemm_qkv8_kernel(
    const u16* __restrict__ A, const u16* __restrict__ Bt,
    const float* __restrict__ bias,
    u16* __restrict__ Qb, u16* __restrict__ Kb, u16* __restrict__ Vt) {
  __shared__ __align__(16) u16 lds[49152];  // 96KB
  int bid = blockIdx.x;
  int sb = (bid & 7) * 96 + (bid >> 3);
  int bx = sb >> 5, by = sb & 31;
  int m0 = by * 128, n0 = bx * 256;

  f32x4 acc[4][4];
  gemm_core_128x256(A, Bt, m0, n0, lds, acc);

  const int tid = threadIdx.x;
  const int wid = tid >> 6, lane = tid & 63;
  const int llo = lane & 15, lhi = lane >> 4;
  const int wm = (wid >> 2) * 64, wn = (wid & 3) * 64;

#pragma unroll
  for (int j = 0; j < 4; ++j) {
    int col = n0 + wn + j * 16 + llo;       // 0..6143
    int h = col / 384;
    int rr = col - h * 384;
    int part = rr >> 7;                     // 0=q 1=k 2=v
    int d = rr & 127;
    float bv = bias[col];
#pragma unroll
    for (int i = 0; i < 4; ++i) {
#pragma unroll
      for (int r = 0; r < 4; ++r) {
        int row = m0 + wm + i * 16 + lhi * 4 + r;  // 0..4095
        int s2 = row >> 1, b = row & 1;
        int bh = b * NHEAD + h;
        u16 o = f2bf(acc[i][j][r] + bv);
        if (part == 0)      Qb[((size_t)bh * S_LEN + s2) * DHEAD + d] = o;
        else if (part == 1) Kb[((size_t)bh * S_LEN + s2) * DHEAD + d] = o;
        else                Vt[((size_t)bh * DHEAD + d) * S_LEN + s2] = o;
      }
    }
  }
}

// ------------- dense GEMM: ctx[4096,2048] x Wt[2048,2048] -> fp32 out --------
__global__ __launch_bounds__(512, 2) void gemm_dense8_kernel(
    const u16* __restrict__ A, const u16* __restrict__ Bt,
    float* __restrict__ out) {
  __shared__ __align__(16) u16 lds[49152];  // 96KB
  int bid = blockIdx.x;                      // 256 blocks = 32/XCD
  int sb = (bid & 7) * 32 + (bid >> 3);
  int bx = sb >> 5, by = sb & 31;
  int m0 = by * 128, n0 = bx * 256;

  f32x4 acc[4][4];
  gemm_core_128x256(A, Bt, m0, n0, lds, acc);

  const int tid = threadIdx.x;
  const int wid = tid >> 6, lane = tid & 63;
  const int llo = lane & 15, lhi = lane >> 4;
  const int wm = (wid >> 2) * 64, wn = (wid & 3) * 64;

#pragma unroll
  for (int i = 0; i < 4; ++i)
#pragma unroll
    for (int j = 0; j < 4; ++j) {
      int col = n0 + wn + j * 16 + llo;
#pragma unroll
      for (int r = 0; r < 4; ++r) {
        int row = m0 + wm + i * 16 + lhi * 4 + r;
        out[(size_t)row * HIDN + col] = acc[i][j][r];
      }
    }
}

// ---------------- flash attention (causal), one block per (q-tile, bh) -------
// (unchanged from round 8 -- passed; global_load_lds double-buffer, no spill)
__global__ __launch_bounds__(512, 2) void attn_kernel(
    const u16* __restrict__ Qb, const u16* __restrict__ Kb,
    const u16* __restrict__ Vt, u16* __restrict__ ctx) {
  const int bh = blockIdx.y;   // 0..31
  const int b = bh >> 4, h = bh & 15;
  const int qi = (b == 0) ? blockIdx.x : (15 - blockIdx.x);
  const int tid = threadIdx.x;
  const int wave = tid >> 6, lane = tid & 63;
  const int lhi = lane >> 4, llo = lane & 15;
  __shared__ __align__(16) u16 lds[65536];  // 128KB: 2 x [K 16384 | V 16384] u16

  const int srow = tid >> 4;                                  // 0..31
  const int scs = ((tid & 15) * 16) ^ ((srow & 7) << 4);      // swizzled byte col
  const int sc2 = scs >> 1;                                   // u16 col
  const u16* kbase = Kb + (size_t)bh * S_LEN * DHEAD;
  const u16* vbase = Vt + (size_t)bh * DHEAD * S_LEN;

#define ASTAGE(T, DST) do {                                                        \
    const u16* ks_ = kbase + (size_t)(T) * 128 * DHEAD;                            \
    const u16* vs_ = vbase + (T) * 128;                                            \
    _Pragma("unroll")                                                              \
    for (int p = 0; p < 4; ++p) {                                                  \
      async_cp16(ks_ + (size_t)(p * 32 + srow) * DHEAD + sc2,                      \
                 (DST) + p * 4096 + wave * 512);                                   \
      async_cp16(vs_ + (size_t)(p * 32 + srow) * S_LEN + sc2,                      \
                 (DST) + 16384 + p * 4096 + wave * 512);                           \
    }                                                                              \
  } while (0)

  bf16x8 aq[4];
  {
    const u16* qsrc = Qb + ((size_t)bh * S_LEN + qi * 128) * DHEAD;
#pragma unroll
    for (int kk = 0; kk < 4; kk++)
      aq[kk] = *(const bf16x8*)&qsrc[(size_t)(wave * 16 + llo) * DHEAD + kk * 32 + lhi * 8];
  }

  f32x4 oacc[8] = {};
  float mrow[4], lrow[4];
#pragma unroll
  for (int r = 0; r < 4; r++) { mrow[r] = -1e30f; lrow[r] = 0.f; }
  const float sc = 0.08838834764831845f;  // 1/sqrt(128)

  int bcol[4];
#pragma unroll
  for (int kk = 0; kk < 4; kk++)
    bcol[kk] = ((kk * 64 + lhi * 16) ^ ((llo & 7) << 4)) >> 1;

  ASTAGE(0, lds);
  asm volatile("s_waitcnt vmcnt(0)" ::: "memory");
  __builtin_amdgcn_s_barrier();
  asm volatile("" ::: "memory");

  for (int kt = 0; kt <= qi; kt++) {
    const int cur = kt & 1;
    u16* Kc = lds + cur * 32768;         // K tile / later P (aliased)
    u16* Vc = Kc + 16384;                // V^T tile [d][t]

    if (kt < qi) ASTAGE(kt + 1, lds + (cur ^ 1) * 32768);

    f32x4 sacc[8] = {};
    __builtin_amdgcn_s_setprio(1);
#pragma unroll
    for (int kk = 0; kk < 4; kk++) {
#pragma unroll
      for (int j = 0; j < 8; j++) {
        bf16x8 bk = *(const bf16x8*)&Kc[(j * 16 + llo) * 128 + bcol[kk]];
        sacc[j] = MFMA16(aq[kk], bk, sacc[j]);
      }
    }
    __builtin_amdgcn_s_setprio(0);
    asm volatile("" ::: "memory");
    __builtin_amdgcn_s_barrier();
    asm volatile("" ::: "memory");

    if (kt == qi) {
#pragma unroll
      for (int j = 0; j < 8; j++) {
        int coll = j * 16 + llo;
#pragma unroll
        for (int r = 0; r < 4; r++) {
          int rowl = wave * 16 + lhi * 4 + r;
          if (coll > rowl) sacc[j][r] = -1e30f;
        }
      }
    }

#pragma unroll
    for (int r = 0; r < 4; r++) {
      float mx = sacc[0][r];
#pragma unroll
      for (int j = 1; j < 8; j++) mx = fmaxf(mx, sacc[j][r]);
#pragma unroll
      for (int off = 1; off < 16; off <<= 1)
        mx = fmaxf(mx, __shfl_xor(mx, off, 64));
      float mnew = fmaxf(mrow[r], mx);
      float al = __expf((mrow[r] - mnew) * sc);
      mrow[r] = mnew;
      float rs = 0.f;
#pragma unroll
      for (int j = 0; j < 8; j++) {
        float e = __expf((sacc[j][r] - mnew) * sc);
        sacc[j][r] = e;
        rs += e;
        oacc[j][r] *= al;
      }
#pragma unroll
      for (int off = 1; off < 16; off <<= 1)
        rs += __shfl_xor(rs, off, 64);
      lrow[r] = lrow[r] * al + rs;
    }

#pragma unroll
    for (int j = 0; j < 8; j++)
#pragma unroll
      for (int r = 0; r < 4; r++) {
        int pr = wave * 16 + lhi * 4 + r;
        int cb = (j * 16 + llo) * 2;
        Kc[pr * 128 + ((cb ^ ((pr & 7) << 4)) >> 1)] = f2bf(sacc[j][r]);
      }

    __builtin_amdgcn_s_setprio(1);
#pragma unroll
    for (int kk = 0; kk < 4; kk++) {
      bf16x8 ap = *(const bf16x8*)&Kc[(wave * 16 + llo) * 128 + bcol[kk]];
#pragma unroll
      for (int j = 0; j < 8; j++) {
        bf16x8 bv = *(const bf16x8*)&Vc[(j * 16 + llo) * 128 + bcol[kk]];
        oacc[j] = MFMA16(ap, bv, oacc[j]);
      }
    }
    __builtin_amdgcn_s_setprio(0);

    asm volatile("s_waitcnt vmcnt(0)" ::: "memory");
    asm volatile("" ::: "memory");
    __builtin_amdgcn_s_barrier();
    asm volatile("" ::: "memory");
  }
#undef ASTAGE

  float inv[4];
#pragma unroll
  for (int r = 0; r < 4; r++) inv[r] = 1.f / lrow[r];
#pragma unroll
  for (int j = 0; j < 8; j++) {
    int d = j * 16 + llo;
#pragma unroll
    for (int r = 0; r < 4; r++) {
      int s = qi * 128 + wave * 16 + lhi * 4 + r;
      ctx[((size_t)(s * BATCH + b)) * HIDN + h * DHEAD + d] = f2bf(oacc[j][r] * inv[r]);
    }
  }
}

// ---------------- bias tail: fp32 copy into output slot 1 --------------------
__global__ __launch_bounds__(256) void bias_copy_kernel(
    const float* __restrict__ bsrc, float* __restrict__ dst) {
  int i = blockIdx.x * 256 + threadIdx.x;
  if (i < HIDN) dst[i] = bsrc[i];
}

extern "C" void kernel_launch(void* const* d_in, const int* in_sizes, int n_in,
                              void* d_out, int out_size, void* d_ws, size_t ws_size,
                              hipStream_t stream) {
  int i_hid = 0, i_w1 = 2, i_b1 = 3, i_w2 = 4, i_b2 = 5;
  for (int i = 0; i < n_in; i++) {
    int s = in_sizes[i];
    if (s == MROWS * HIDN)      i_hid = i;
    else if (s == HIDN * NQKV)  i_w1 = i;
    else if (s == NQKV)         i_b1 = i;
    else if (s == HIDN)         i_b2 = i;
  }
  for (int i = n_in - 1; i >= 0; i--)
    if (in_sizes[i] == HIDN * HIDN) { i_w2 = i; break; }

  const float* hidden  = (const float*)d_in[i_hid];
  const float* W_qkv   = (const float*)d_in[i_w1];
  const float* b_qkv   = (const float*)d_in[i_b1];
  const float* W_dense = (const float*)d_in[i_w2];
  const float* b_dense = (const float*)d_in[i_b2];
  float* out = (float*)d_out;

  char* ws = (char*)d_ws;
  u16* Wq_t = (u16*)(ws);
  u16* ctx  = (u16*)(ws);
  u16* Wd_t = (u16*)(ws + 16777216);
  u16* Qb   = (u16*)(ws + 25165824);
  u16* Kb   = (u16*)(ws + 41943040);
  u16* Vt   = (u16*)(ws + 58720256);
  u16* hidden_c = (u16*)d_out;

  convert_hidden_kernel<<<dim3(MROWS * HIDN / 8 / 256), 256, 0, stream>>>(hidden, hidden_c);
  transpose_kernel<<<dim3(NQKV / 64, HIDN / 64), 256, 0, stream>>>(W_qkv, Wq_t, HIDN, NQKV);
  gemm_qkv8_kernel<<<dim3(768), dim3(512), 0, stream>>>(hidden_c, Wq_t, b_qkv, Qb, Kb, Vt);
  attn_kernel<<<dim3(S_LEN / 128, BATCH * NHEAD), dim3(512), 0, stream>>>(Qb, Kb, Vt, ctx);
  transpose_kernel<<<dim3(HIDN / 64, HIDN / 64), 256, 0, stream>>>(W_dense, Wd_t, HIDN, HIDN);
  gemm_dense8_kernel<<<dim3(256), dim3(512), 0, stream>>>(ctx, Wd_t, out);
  bias_copy_kernel<<<dim3(8), 256, 0, stream>>>(b_dense, out + (size_t)MROWS * HIDN);
}